// Round 6
// baseline (382.003 us; speedup 1.0000x reference)
//
#include <hip/hip_runtime.h>
#include <hip/hip_bf16.h>

typedef __hip_bfloat16 bf16;
using short8 = __attribute__((ext_vector_type(8))) short;
using f32x4  = __attribute__((ext_vector_type(4))) float;

#ifndef __has_builtin
#define __has_builtin(x) 0
#endif
#if __has_builtin(__builtin_amdgcn_global_load_lds)
#define HAVE_GLL 1
#else
#define HAVE_GLL 0
#endif

__device__ inline void stage16(const short* __restrict__ g, short* l, int lane) {
#if HAVE_GLL
  __builtin_amdgcn_global_load_lds((__attribute__((address_space(1))) void*)g,
                                   (__attribute__((address_space(3))) void*)l,
                                   16, 0, 0);
#else
  *(short8*)(l + lane * 8) = *(const short8*)g;
#endif
}

__device__ inline unsigned pack2bf(float a, float b) {
  bf16 h0 = __float2bfloat16(a), h1 = __float2bfloat16(b);
  return (unsigned)*(unsigned short*)&h0 | ((unsigned)*(unsigned short*)&h1 << 16);
}

__device__ inline short bfbits(float v) {
  bf16 h = __float2bfloat16(v);
  return *(short*)&h;
}

// ---------------------------------------------------------------------------
// LDS-staged batched GEMM (m97 structure): C = alpha*A@B^T (+bias[col]).
// Tile 128 x BN (BN=64|128), BK=64. A:[M,K](lda) bf16, B:[N,K](ldb) bf16,
// C bf16 or fp32. 256 thr = 4 waves 2x2; wave = 4 x (BN/32) mfma 16x16x32.
// ---------------------------------------------------------------------------
template <int BN>
__global__ __launch_bounds__(256) void gemm_lds(
    const bf16* __restrict__ Ag, long a_bs1, long a_bs2, int lda,
    const bf16* __restrict__ Bg, long b_bs1, long b_bs2, int ldb,
    void* __restrict__ Cg, long c_bs1, long c_bs2, int ldc,
    const float* __restrict__ bias, int K, int Z2, float alpha, int cf32)
{
  constexpr int WNT = BN / 32;
  __shared__ short As[128 * 64];
  __shared__ short Bs[BN * 64];

  int z = blockIdx.z, z1 = z / Z2, z2 = z - z1 * Z2;
  const short* A = (const short*)(Ag + z1 * a_bs1 + z2 * a_bs2);
  const short* B = (const short*)(Bg + z1 * b_bs1 + z2 * b_bs2);

  int tid = threadIdx.x, lane = tid & 63, w = tid >> 6;
  int wm = w & 1, wn = w >> 1;
  int m0 = blockIdx.x * 128, n0 = blockIdx.y * BN;
  int r = lane & 15, q = lane >> 4;

  int srow = lane >> 3, scol = (lane & 7) * 8;
  const short* Asrc = A + (long)(m0 + w * 32 + srow) * lda + scol;
  const short* Bsrc = B + (long)(n0 + w * (BN / 4) + srow) * ldb + scol;
  short* Adst = As + (w * 32) * 64;
  short* Bdst = Bs + (w * (BN / 4)) * 64;

  f32x4 acc[4][WNT];
  #pragma unroll
  for (int i = 0; i < 4; ++i)
    #pragma unroll
    for (int j = 0; j < WNT; ++j) acc[i][j] = (f32x4){0.f, 0.f, 0.f, 0.f};

  for (int kt = 0; kt < K; kt += 64) {
    #pragma unroll
    for (int i = 0; i < 4; ++i)
      stage16(Asrc + (long)i * 8 * lda + kt, Adst + i * 8 * 64, lane);
    #pragma unroll
    for (int i = 0; i < BN / 32; ++i)
      stage16(Bsrc + (long)i * 8 * ldb + kt, Bdst + i * 8 * 64, lane);
    __syncthreads();
    #pragma unroll
    for (int kk = 0; kk < 64; kk += 32) {
      short8 af[4], bfr[WNT];
      #pragma unroll
      for (int i = 0; i < 4; ++i)
        af[i] = *(const short8*)&As[(wm * 64 + i * 16 + r) * 64 + kk + q * 8];
      #pragma unroll
      for (int j = 0; j < WNT; ++j)
        bfr[j] = *(const short8*)&Bs[(wn * WNT * 16 + j * 16 + r) * 64 + kk + q * 8];
      #pragma unroll
      for (int i = 0; i < 4; ++i)
        #pragma unroll
        for (int j = 0; j < WNT; ++j)
          acc[i][j] = __builtin_amdgcn_mfma_f32_16x16x32_bf16(af[i], bfr[j], acc[i][j], 0, 0, 0);
    }
    __syncthreads();
  }

  long cb = z1 * c_bs1 + z2 * c_bs2;
  #pragma unroll
  for (int j = 0; j < WNT; ++j) {
    int col = n0 + wn * WNT * 16 + j * 16 + r;
    float bv = bias ? bias[col] : 0.0f;
    #pragma unroll
    for (int i = 0; i < 4; ++i) {
      int row0 = m0 + wm * 64 + i * 16 + q * 4;
      #pragma unroll
      for (int rr = 0; rr < 4; ++rr) {
        float val = acc[i][j][rr] * alpha + bv;
        long idx = cb + (long)(row0 + rr) * ldc + col;
        if (cf32) ((float*)Cg)[idx] = val;
        else ((bf16*)Cg)[idx] = __float2bfloat16(val);
      }
    }
  }
}

// ---------------------------------------------------------------------------
// Fused z-batched QKV projection, 128x128 tile (gemm_lds<128> body).
// ---------------------------------------------------------------------------
struct QKVArgs {
  const bf16* A[3];
  const bf16* Bw[3];
  bf16* C[3];
  const float* bias[3];
};

__global__ __launch_bounds__(256) void gemm_qkv(QKVArgs args) {
  __shared__ short As[128 * 64];
  __shared__ short Bs[128 * 64];

  int z = blockIdx.z;
  const short* A = (const short*)args.A[z];
  const short* B = (const short*)args.Bw[z];
  bf16* C = args.C[z];
  const float* bias = args.bias[z];

  int tid = threadIdx.x, lane = tid & 63, w = tid >> 6;
  int wm = w & 1, wn = w >> 1;
  int m0 = blockIdx.x * 128, n0 = blockIdx.y * 128;
  int r = lane & 15, q = lane >> 4;

  int srow = lane >> 3, scol = (lane & 7) * 8;
  const short* Asrc = A + (long)(m0 + w * 32 + srow) * 1024 + scol;
  const short* Bsrc = B + (long)(n0 + w * 32 + srow) * 1024 + scol;
  short* Adst = As + (w * 32) * 64;
  short* Bdst = Bs + (w * 32) * 64;

  f32x4 acc[4][4];
  #pragma unroll
  for (int i = 0; i < 4; ++i)
    #pragma unroll
    for (int j = 0; j < 4; ++j) acc[i][j] = (f32x4){0.f, 0.f, 0.f, 0.f};

  for (int kt = 0; kt < 1024; kt += 64) {
    #pragma unroll
    for (int i = 0; i < 4; ++i)
      stage16(Asrc + (long)i * 8 * 1024 + kt, Adst + i * 8 * 64, lane);
    #pragma unroll
    for (int i = 0; i < 4; ++i)
      stage16(Bsrc + (long)i * 8 * 1024 + kt, Bdst + i * 8 * 64, lane);
    __syncthreads();
    #pragma unroll
    for (int kk = 0; kk < 64; kk += 32) {
      short8 af[4], bfr[4];
      #pragma unroll
      for (int i = 0; i < 4; ++i)
        af[i] = *(const short8*)&As[(wm * 64 + i * 16 + r) * 64 + kk + q * 8];
      #pragma unroll
      for (int j = 0; j < 4; ++j)
        bfr[j] = *(const short8*)&Bs[(wn * 64 + j * 16 + r) * 64 + kk + q * 8];
      #pragma unroll
      for (int i = 0; i < 4; ++i)
        #pragma unroll
        for (int j = 0; j < 4; ++j)
          acc[i][j] = __builtin_amdgcn_mfma_f32_16x16x32_bf16(af[i], bfr[j], acc[i][j], 0, 0, 0);
    }
    __syncthreads();
  }

  #pragma unroll
  for (int j = 0; j < 4; ++j) {
    int col = n0 + wn * 64 + j * 16 + r;
    float bv = bias[col];
    #pragma unroll
    for (int i = 0; i < 4; ++i) {
      int row0 = m0 + wm * 64 + i * 16 + q * 4;
      #pragma unroll
      for (int rr = 0; rr < 4; ++rr)
        C[(long)(row0 + rr) * 1024 + col] = __float2bfloat16(acc[i][j][rr] + bv);
    }
  }
}

// ---------------------------------------------------------------------------
// Direct (no-LDS) K=64 batched GEMM for scores: tile 128x128, wave 64x64.
// ---------------------------------------------------------------------------
__global__ __launch_bounds__(256) void gemm_k64(
    const bf16* __restrict__ Ag, long a_bs1, long a_bs2, int lda,
    const bf16* __restrict__ Bg, long b_bs1, long b_bs2, int ldb,
    bf16* __restrict__ Cg, long c_bs1, long c_bs2, int ldc,
    int Z2, float alpha)
{
  int z = blockIdx.z, z1 = z / Z2, z2 = z - z1 * Z2;
  const short* A = (const short*)(Ag + z1 * a_bs1 + z2 * a_bs2);
  const short* B = (const short*)(Bg + z1 * b_bs1 + z2 * b_bs2);
  bf16* C = Cg + z1 * c_bs1 + z2 * c_bs2;

  int tid = threadIdx.x, lane = tid & 63, w = tid >> 6;
  int wm = w & 1, wn = w >> 1;
  int m0 = blockIdx.x * 128 + wm * 64;
  int n0 = blockIdx.y * 128 + wn * 64;
  int r = lane & 15, q = lane >> 4;

  const short* Ar = A + (long)(m0 + r) * lda + q * 8;
  const short* Br = B + (long)(n0 + r) * ldb + q * 8;

  f32x4 acc[4][4];
  #pragma unroll
  for (int i = 0; i < 4; ++i)
    #pragma unroll
    for (int j = 0; j < 4; ++j) acc[i][j] = (f32x4){0.f, 0.f, 0.f, 0.f};

  #pragma unroll
  for (int kk = 0; kk < 64; kk += 32) {
    short8 af[4], bfr[4];
    #pragma unroll
    for (int i = 0; i < 4; ++i) af[i] = *(const short8*)(Ar + (long)i * 16 * lda + kk);
    #pragma unroll
    for (int j = 0; j < 4; ++j) bfr[j] = *(const short8*)(Br + (long)j * 16 * ldb + kk);
    #pragma unroll
    for (int i = 0; i < 4; ++i)
      #pragma unroll
      for (int j = 0; j < 4; ++j)
        acc[i][j] = __builtin_amdgcn_mfma_f32_16x16x32_bf16(af[i], bfr[j], acc[i][j], 0, 0, 0);
  }

  #pragma unroll
  for (int j = 0; j < 4; ++j) {
    int col = n0 + j * 16 + r;
    #pragma unroll
    for (int i = 0; i < 4; ++i) {
      int row0 = m0 + i * 16 + q * 4;
      #pragma unroll
      for (int rr = 0; rr < 4; ++rr)
        C[(long)(row0 + rr) * ldc + col] = __float2bfloat16(acc[i][j][rr] * alpha);
    }
  }
}

// ---------------------------------------------------------------------------
// Fused fp32->bf16 converts for from/to.
// ---------------------------------------------------------------------------
__global__ __launch_bounds__(256) void cvt2(
    const float* __restrict__ a, const float* __restrict__ b,
    bf16* __restrict__ oa, bf16* __restrict__ ob)
{
  const float* in = blockIdx.y ? b : a;
  bf16* out = blockIdx.y ? ob : oa;
  int i = (blockIdx.x * 256 + threadIdx.x) * 8;
  float4 v0 = *(const float4*)(in + i);
  float4 v1 = *(const float4*)(in + i + 4);
  uint4 pk;
  pk.x = pack2bf(v0.x, v0.y);
  pk.y = pack2bf(v0.z, v0.w);
  pk.z = pack2bf(v1.x, v1.y);
  pk.w = pack2bf(v1.z, v1.w);
  *(uint4*)(out + i) = pk;
}

// ---------------------------------------------------------------------------
// Fused 4-way weight transpose: fp32 [1024,1024] -> bf16 transposed.
// ---------------------------------------------------------------------------
struct WT4 { const float* s[4]; bf16* d[4]; };

__global__ __launch_bounds__(256) void wtrans4(WT4 a) {
  __shared__ bf16 tile[64][66];
  int z = blockIdx.z;
  const float* in = a.s[z];
  bf16* out = a.d[z];
  int r0 = blockIdx.x * 64, c0 = blockIdx.y * 64;
  int tx = threadIdx.x & 63, ty = threadIdx.x >> 6;
  #pragma unroll
  for (int i = 0; i < 16; ++i) {
    int rr = i * 4 + ty;
    tile[rr][tx] = __float2bfloat16(in[(long)(r0 + rr) * 1024 + c0 + tx]);
  }
  __syncthreads();
  #pragma unroll
  for (int i = 0; i < 16; ++i) {
    int rr = i * 4 + ty;
    out[(long)(c0 + rr) * 1024 + r0 + tx] = tile[tx][rr];
  }
}

// ---------------------------------------------------------------------------
// Batched 64x64-tiled bf16 transpose (V -> Vt).
// ---------------------------------------------------------------------------
__global__ __launch_bounds__(256) void transpose_bf16(
    const bf16* __restrict__ in, long i_bs1, long i_bs2, int i_rs,
    bf16* __restrict__ out, long o_bs1, long o_bs2, int o_rs, int Z2)
{
  __shared__ bf16 tile[64][66];
  int z = blockIdx.z, z1 = z / Z2, z2 = z - z1 * Z2;
  const bf16* ib = in + z1 * i_bs1 + z2 * i_bs2;
  bf16* ob = out + z1 * o_bs1 + z2 * o_bs2;
  int r0 = blockIdx.x * 64, c0 = blockIdx.y * 64;
  int tx = threadIdx.x & 63, ty = threadIdx.x >> 6;
  #pragma unroll
  for (int i = 0; i < 16; ++i) {
    int rr = i * 4 + ty;
    tile[rr][tx] = ib[(long)(r0 + rr) * i_rs + c0 + tx];
  }
  __syncthreads();
  #pragma unroll
  for (int i = 0; i < 16; ++i) {
    int rr = i * 4 + ty;
    ob[(long)(c0 + rr) * o_rs + r0 + tx] = tile[tx][rr];
  }
}

// ---------------------------------------------------------------------------
// Talking-heads core v3: the 16x16 head-mixes moved to MFMA.
// mix = W(16x16) applied per t: use mfma_f32_16x16x32_bf16 with K zero-padded
// 16->32 in the A operand (A[.,k>=16]=0 kills those terms regardless of B).
// Block = (f,b), 4 waves; wave owns 256 t (16 steps of 16 t).
//   pass A: b1 gathered from LDS-staged Sc (stride 1028 -> conflict-free),
//           mask folded into the MFMA's C operand; exp + Z-accumulate.
//           E kept in registers (64 f32/thread, D-layout).
//   pass B: b2 built by 8 __shfl from D-layout (no LDS transpose); mfma with
//           post-weights; scalar bf16 stores.
// ---------------------------------------------------------------------------
#define SST 1028

__global__ __launch_bounds__(256) void mixsoftmax3(
    bf16* __restrict__ sc, long sc_bs, const float* __restrict__ pre,
    const float* __restrict__ post, const int* __restrict__ mask)
{
  __shared__ short scs[16 * SST];
  __shared__ float zpart[4][16];
  __shared__ float zinvs[16];

  int tid = threadIdx.x, lane = tid & 63, w = tid >> 6;
  int q = lane >> 4, r = lane & 15, qq = q & 1;
  int f = blockIdx.x, b = blockIdx.y;

  short* scb = (short*)(sc + (long)b * sc_bs) + ((long)f << 10);
  const int* mk = mask + ((long)b << 20) + ((long)f << 10);

  // stage the 16 head-rows of this f into LDS (coalesced 8B chunks)
  #pragma unroll
  for (int i = 0; i < 16; ++i) {
    int s = i * 256 + tid;
    int n = s >> 8, off = (s & 255) * 4;
    *(uint2*)&scs[n * SST + off] = *(const uint2*)(scb + ((long)n << 20) + off);
  }

  // A-fragments: a[j] = W[q*8+j][r], zero for k>=16 (q>=2)
  short8 a1 = {}, a2 = {};
  #pragma unroll
  for (int j = 0; j < 8; ++j) {
    int n = q * 8 + j;
    float v1 = (q < 2) ? pre[(n & 15) * 16 + r] : 0.0f;
    float v2 = (q < 2) ? post[(n & 15) * 16 + r] : 0.0f;
    a1[j] = bfbits(v1);
    a2[j] = bfbits(v2);
  }
  __syncthreads();

  int wt0 = w * 256;
  float E[16][4];
  float zl[4] = {0.f, 0.f, 0.f, 0.f};

  #pragma unroll
  for (int s = 0; s < 16; ++s) {
    int t0 = wt0 + s * 16;
    short8 b1;
    #pragma unroll
    for (int j = 0; j < 8; ++j)
      b1[j] = scs[(qq * 8 + j) * SST + t0 + r];  // q>=2: harmless (A is 0 there)
    float madd = (1.0f - (float)mk[t0 + r]) * -10000.0f;
    f32x4 c = {madd, madd, madd, madd};
    f32x4 d = __builtin_amdgcn_mfma_f32_16x16x32_bf16(a1, b1, c, 0, 0, 0);
    #pragma unroll
    for (int g = 0; g < 4; ++g) {
      float e = __expf(d[g]);
      E[s][g] = e;
      zl[g] += e;
    }
  }

  // Z[l]: reduce over the 16 r-lanes of each quad, then across waves via LDS
  #pragma unroll
  for (int off = 8; off >= 1; off >>= 1)
    #pragma unroll
    for (int g = 0; g < 4; ++g)
      zl[g] += __shfl_down(zl[g], off);
  if (r == 0)
    #pragma unroll
    for (int g = 0; g < 4; ++g)
      zpart[w][q * 4 + g] = zl[g];
  __syncthreads();
  if (tid < 16)
    zinvs[tid] = 1.0f / (zpart[0][tid] + zpart[1][tid] + zpart[2][tid] + zpart[3][tid]);
  __syncthreads();

  float zi[4];
  #pragma unroll
  for (int g = 0; g < 4; ++g) zi[g] = zinvs[q * 4 + g];

  #pragma unroll
  for (int s = 0; s < 16; ++s) {
    int t0 = wt0 + s * 16;
    float pe[4];
    #pragma unroll
    for (int g = 0; g < 4; ++g) pe[g] = E[s][g] * zi[g];
    // b2[j] = P_hat[n=qq*8+j][t0+r], pulled from lane ((n>>2)<<4)+r reg n&3
    short8 b2;
    #pragma unroll
    for (int j = 0; j < 8; ++j) {
      int n = qq * 8 + j;
      float v = __shfl(pe[n & 3], ((n >> 2) << 4) + r);
      b2[j] = bfbits(v);
    }
    f32x4 zero = {0.f, 0.f, 0.f, 0.f};
    f32x4 p = __builtin_amdgcn_mfma_f32_16x16x32_bf16(a2, b2, zero, 0, 0, 0);
    #pragma unroll
    for (int g = 0; g < 4; ++g)
      scb[((long)(q * 4 + g) << 20) + t0 + r] = bfbits(p[g]);
  }
}

// ---------------------------------------------------------------------------
// B=4, S=1024, D=1024, N=16, H=64. fp32 I/O, bf16 internal.
// ws (bf16 elems, M1=1<<20): big path 85M = 170 MB, small path 37M = 74 MB.
// ---------------------------------------------------------------------------
extern "C" void kernel_launch(void* const* d_in, const int* in_sizes, int n_in,
                              void* d_out, int out_size, void* d_ws, size_t ws_size,
                              hipStream_t stream) {
  const float* from = (const float*)d_in[0];
  const float* to   = (const float*)d_in[1];
  const int*  mask  = (const int*)d_in[2];
  const float* wq = (const float*)d_in[3];
  const float* bq = (const float*)d_in[4];
  const float* wk = (const float*)d_in[5];
  const float* bk = (const float*)d_in[6];
  const float* wv = (const float*)d_in[7];
  const float* bv = (const float*)d_in[8];
  const float* pre  = (const float*)d_in[9];
  const float* post = (const float*)d_in[10];
  const float* wo = (const float*)d_in[11];
  const float* bo = (const float*)d_in[12];
  float* out = (float*)d_out;

  bf16* W = (bf16*)d_ws;
  const long M1 = 1048576;
  bool big = ws_size >= (size_t)(85 * M1) * 2;

  bf16 *Sc, *fromB, *toB, *wqT, *wkT, *wvT, *woT, *Q, *Kp, *V, *Vt, *ctx;
  if (big) {
    Sc = W;                 fromB = W;            toB = W + 4 * M1;
    wqT = W + 8 * M1;       wkT = W + 9 * M1;     wvT = W + 10 * M1;
    woT = W + 64 * M1;      Q = W + 65 * M1;      Kp = W + 69 * M1;
    V = W + 73 * M1;        Vt = W + 77 * M1;     ctx = W + 81 * M1;
  } else {
    Sc = W;                 fromB = W;            toB = W + 4 * M1;
    wqT = W + 8 * M1;       wkT = W + 9 * M1;     wvT = W + 10 * M1;
    woT = W + 16 * M1;      Q = W + 17 * M1;      Kp = W + 21 * M1;
    V = W + 25 * M1;        Vt = W + 29 * M1;     ctx = W + 33 * M1;
  }

  dim3 blk(256);

  // 1) converts + weight transposes
  cvt2<<<dim3(2048, 2), blk, 0, stream>>>(from, to, fromB, toB);
  WT4 wt;
  wt.s[0] = wq; wt.s[1] = wk; wt.s[2] = wv; wt.s[3] = wo;
  wt.d[0] = wqT; wt.d[1] = wkT; wt.d[2] = wvT; wt.d[3] = woT;
  wtrans4<<<dim3(16, 16, 4), blk, 0, stream>>>(wt);

  // 2) QKV projections, z-batched, 128x128 tiles (768 blocks = 3/CU)
  QKVArgs qa;
  qa.A[0] = fromB; qa.A[1] = toB; qa.A[2] = toB;
  qa.Bw[0] = wqT;  qa.Bw[1] = wkT; qa.Bw[2] = wvT;
  qa.C[0] = Q;     qa.C[1] = Kp;  qa.C[2] = V;
  qa.bias[0] = bq; qa.bias[1] = bk; qa.bias[2] = bv;
  gemm_qkv<<<dim3(32, 8, 3), blk, 0, stream>>>(qa);

  // 3) V [B,S,N,H] -> Vt [B,N,H,S]
  transpose_bf16<<<dim3(16, 1, 64), blk, 0, stream>>>(V, M1, 64, 1024,
                                                      Vt, M1, 65536, 1024, 16);

  if (big) {
    // 4) scores (direct K=64): z=(b,n): Sc[b,n] = 0.125*Q[b,:,n,:]@K[b,:,n,:]^T
    gemm_k64<<<dim3(8, 8, 64), blk, 0, stream>>>(
        Q, M1, 64, 1024, Kp, M1, 64, 1024, Sc, 16 * M1, M1, 1024, 16, 0.125f);
    // 5) talking-heads softmax (MFMA mixes)
    mixsoftmax3<<<dim3(1024, 4), blk, 0, stream>>>(Sc, 16 * M1, pre, post, mask);
    // 6) PV: z=(b,l): ctx[b,:,l,:] = Sc[b,l]@Vt[b,l]^T
    gemm_lds<64><<<dim3(8, 1, 64), blk, 0, stream>>>(
        Sc, 16 * M1, M1, 1024, Vt, M1, 65536, 1024, ctx, M1, 64, 1024, nullptr,
        1024, 16, 1.0f, 0);
  } else {
    for (int b = 0; b < 4; ++b) {
      gemm_k64<<<dim3(8, 8, 16), blk, 0, stream>>>(
          Q + b * M1, 0, 64, 1024, Kp + b * M1, 0, 64, 1024,
          Sc, 0, M1, 1024, 16, 0.125f);
      mixsoftmax3<<<dim3(1024, 1), blk, 0, stream>>>(Sc, 0, pre, post, mask + b * M1);
      gemm_lds<64><<<dim3(8, 1, 16), blk, 0, stream>>>(
          Sc, 0, M1, 1024, Vt + b * M1, 0, 65536, 1024,
          ctx + b * M1, 0, 64, 1024, nullptr, 1024, 16, 1.0f, 0);
    }
  }

  // 7) out = ctx [4096,1024] @ woT^T + bo -> d_out (fp32), 128x128 tiles
  gemm_lds<128><<<dim3(32, 8, 1), blk, 0, stream>>>(
      ctx, 0, 0, 1024, woT, 0, 0, 1024, out, 0, 0, 1024, bo, 1024, 1, 1.0f, 1);
}

// Round 7
// 364.317 us; speedup vs baseline: 1.0485x; 1.0485x over previous
//
#include <hip/hip_runtime.h>
#include <hip/hip_bf16.h>

typedef __hip_bfloat16 bf16;
using short8 = __attribute__((ext_vector_type(8))) short;
using f32x4  = __attribute__((ext_vector_type(4))) float;
using f32x2  = __attribute__((ext_vector_type(2))) float;

#ifndef __has_builtin
#define __has_builtin(x) 0
#endif
#if __has_builtin(__builtin_amdgcn_global_load_lds)
#define HAVE_GLL 1
#else
#define HAVE_GLL 0
#endif

__device__ inline void stage16(const short* __restrict__ g, short* l, int lane) {
#if HAVE_GLL
  __builtin_amdgcn_global_load_lds((__attribute__((address_space(1))) void*)g,
                                   (__attribute__((address_space(3))) void*)l,
                                   16, 0, 0);
#else
  *(short8*)(l + lane * 8) = *(const short8*)g;
#endif
}

__device__ inline unsigned pack2bf(float a, float b) {
  bf16 h0 = __float2bfloat16(a), h1 = __float2bfloat16(b);
  return (unsigned)*(unsigned short*)&h0 | ((unsigned)*(unsigned short*)&h1 << 16);
}

// ---------------------------------------------------------------------------
// LDS-staged batched GEMM, tile 128x64, BK=64 (m97 structure). C = alpha*A@B^T
// (+bias). A:[M,K](lda) bf16, B:[N,K](ldb) bf16, C bf16 or fp32.
// ---------------------------------------------------------------------------
__global__ __launch_bounds__(256) void gemm_lds64(
    const bf16* __restrict__ Ag, long a_bs1, long a_bs2, int lda,
    const bf16* __restrict__ Bg, long b_bs1, long b_bs2, int ldb,
    void* __restrict__ Cg, long c_bs1, long c_bs2, int ldc,
    const float* __restrict__ bias, int K, int Z2, float alpha, int cf32)
{
  __shared__ short As[128 * 64];
  __shared__ short Bs[64 * 64];

  int z = blockIdx.z, z1 = z / Z2, z2 = z - z1 * Z2;
  const short* A = (const short*)(Ag + z1 * a_bs1 + z2 * a_bs2);
  const short* B = (const short*)(Bg + z1 * b_bs1 + z2 * b_bs2);

  int tid = threadIdx.x, lane = tid & 63, w = tid >> 6;
  int wm = w & 1, wn = w >> 1;
  int m0 = blockIdx.x * 128, n0 = blockIdx.y * 64;
  int r = lane & 15, q = lane >> 4;

  int srow = lane >> 3, scol = (lane & 7) * 8;
  const short* Asrc = A + (long)(m0 + w * 32 + srow) * lda + scol;
  const short* Bsrc = B + (long)(n0 + w * 16 + srow) * ldb + scol;
  short* Adst = As + (w * 32) * 64;
  short* Bdst = Bs + (w * 16) * 64;

  f32x4 acc[4][2];
  #pragma unroll
  for (int i = 0; i < 4; ++i)
    #pragma unroll
    for (int j = 0; j < 2; ++j) acc[i][j] = (f32x4){0.f, 0.f, 0.f, 0.f};

  for (int kt = 0; kt < K; kt += 64) {
    #pragma unroll
    for (int i = 0; i < 4; ++i)
      stage16(Asrc + (long)i * 8 * lda + kt, Adst + i * 8 * 64, lane);
    #pragma unroll
    for (int i = 0; i < 2; ++i)
      stage16(Bsrc + (long)i * 8 * ldb + kt, Bdst + i * 8 * 64, lane);
    __syncthreads();
    #pragma unroll
    for (int kk = 0; kk < 64; kk += 32) {
      short8 af[4], bfr[2];
      #pragma unroll
      for (int i = 0; i < 4; ++i)
        af[i] = *(const short8*)&As[(wm * 64 + i * 16 + r) * 64 + kk + q * 8];
      #pragma unroll
      for (int j = 0; j < 2; ++j)
        bfr[j] = *(const short8*)&Bs[(wn * 32 + j * 16 + r) * 64 + kk + q * 8];
      #pragma unroll
      for (int i = 0; i < 4; ++i)
        #pragma unroll
        for (int j = 0; j < 2; ++j)
          acc[i][j] = __builtin_amdgcn_mfma_f32_16x16x32_bf16(af[i], bfr[j], acc[i][j], 0, 0, 0);
    }
    __syncthreads();
  }

  long cb = z1 * c_bs1 + z2 * c_bs2;
  #pragma unroll
  for (int j = 0; j < 2; ++j) {
    int col = n0 + wn * 32 + j * 16 + r;
    float bv = bias ? bias[col] : 0.0f;
    #pragma unroll
    for (int i = 0; i < 4; ++i) {
      int row0 = m0 + wm * 64 + i * 16 + q * 4;
      #pragma unroll
      for (int rr = 0; rr < 4; ++rr) {
        float val = acc[i][j][rr] * alpha + bv;
        long idx = cb + (long)(row0 + rr) * ldc + col;
        if (cf32) ((float*)Cg)[idx] = val;
        else ((bf16*)Cg)[idx] = __float2bfloat16(val);
      }
    }
  }
}

// ---------------------------------------------------------------------------
// Fused z-batched QKV projection: z=0,1,2 -> Q,K,V. gemm_lds64 body,
// M=4096, N=1024, K=1024, ld*=1024.
// ---------------------------------------------------------------------------
struct QKVArgs {
  const bf16* A[3];
  const bf16* Bw[3];
  bf16* C[3];
  const float* bias[3];
};

__global__ __launch_bounds__(256) void gemm_qkv(QKVArgs args) {
  __shared__ short As[128 * 64];
  __shared__ short Bs[64 * 64];

  int z = blockIdx.z;
  const short* A = (const short*)args.A[z];
  const short* B = (const short*)args.Bw[z];
  bf16* C = args.C[z];
  const float* bias = args.bias[z];

  int tid = threadIdx.x, lane = tid & 63, w = tid >> 6;
  int wm = w & 1, wn = w >> 1;
  int m0 = blockIdx.x * 128, n0 = blockIdx.y * 64;
  int r = lane & 15, q = lane >> 4;

  int srow = lane >> 3, scol = (lane & 7) * 8;
  const short* Asrc = A + (long)(m0 + w * 32 + srow) * 1024 + scol;
  const short* Bsrc = B + (long)(n0 + w * 16 + srow) * 1024 + scol;
  short* Adst = As + (w * 32) * 64;
  short* Bdst = Bs + (w * 16) * 64;

  f32x4 acc[4][2];
  #pragma unroll
  for (int i = 0; i < 4; ++i)
    #pragma unroll
    for (int j = 0; j < 2; ++j) acc[i][j] = (f32x4){0.f, 0.f, 0.f, 0.f};

  for (int kt = 0; kt < 1024; kt += 64) {
    #pragma unroll
    for (int i = 0; i < 4; ++i)
      stage16(Asrc + (long)i * 8 * 1024 + kt, Adst + i * 8 * 64, lane);
    #pragma unroll
    for (int i = 0; i < 2; ++i)
      stage16(Bsrc + (long)i * 8 * 1024 + kt, Bdst + i * 8 * 64, lane);
    __syncthreads();
    #pragma unroll
    for (int kk = 0; kk < 64; kk += 32) {
      short8 af[4], bfr[2];
      #pragma unroll
      for (int i = 0; i < 4; ++i)
        af[i] = *(const short8*)&As[(wm * 64 + i * 16 + r) * 64 + kk + q * 8];
      #pragma unroll
      for (int j = 0; j < 2; ++j)
        bfr[j] = *(const short8*)&Bs[(wn * 32 + j * 16 + r) * 64 + kk + q * 8];
      #pragma unroll
      for (int i = 0; i < 4; ++i)
        #pragma unroll
        for (int j = 0; j < 2; ++j)
          acc[i][j] = __builtin_amdgcn_mfma_f32_16x16x32_bf16(af[i], bfr[j], acc[i][j], 0, 0, 0);
    }
    __syncthreads();
  }

  #pragma unroll
  for (int j = 0; j < 2; ++j) {
    int col = n0 + wn * 32 + j * 16 + r;
    float bv = bias[col];
    #pragma unroll
    for (int i = 0; i < 4; ++i) {
      int row0 = m0 + wm * 64 + i * 16 + q * 4;
      #pragma unroll
      for (int rr = 0; rr < 4; ++rr)
        C[(long)(row0 + rr) * 1024 + col] = __float2bfloat16(acc[i][j][rr] + bv);
    }
  }
}

// ---------------------------------------------------------------------------
// Direct (no-LDS) K=64 batched GEMM for scores: tile 128x128, wave 64x64.
// ---------------------------------------------------------------------------
__global__ __launch_bounds__(256) void gemm_k64(
    const bf16* __restrict__ Ag, long a_bs1, long a_bs2, int lda,
    const bf16* __restrict__ Bg, long b_bs1, long b_bs2, int ldb,
    bf16* __restrict__ Cg, long c_bs1, long c_bs2, int ldc,
    int Z2, float alpha)
{
  int z = blockIdx.z, z1 = z / Z2, z2 = z - z1 * Z2;
  const short* A = (const short*)(Ag + z1 * a_bs1 + z2 * a_bs2);
  const short* B = (const short*)(Bg + z1 * b_bs1 + z2 * b_bs2);
  bf16* C = Cg + z1 * c_bs1 + z2 * c_bs2;

  int tid = threadIdx.x, lane = tid & 63, w = tid >> 6;
  int wm = w & 1, wn = w >> 1;
  int m0 = blockIdx.x * 128 + wm * 64;
  int n0 = blockIdx.y * 128 + wn * 64;
  int r = lane & 15, q = lane >> 4;

  const short* Ar = A + (long)(m0 + r) * lda + q * 8;
  const short* Br = B + (long)(n0 + r) * ldb + q * 8;

  f32x4 acc[4][4];
  #pragma unroll
  for (int i = 0; i < 4; ++i)
    #pragma unroll
    for (int j = 0; j < 4; ++j) acc[i][j] = (f32x4){0.f, 0.f, 0.f, 0.f};

  #pragma unroll
  for (int kk = 0; kk < 64; kk += 32) {
    short8 af[4], bfr[4];
    #pragma unroll
    for (int i = 0; i < 4; ++i) af[i] = *(const short8*)(Ar + (long)i * 16 * lda + kk);
    #pragma unroll
    for (int j = 0; j < 4; ++j) bfr[j] = *(const short8*)(Br + (long)j * 16 * ldb + kk);
    #pragma unroll
    for (int i = 0; i < 4; ++i)
      #pragma unroll
      for (int j = 0; j < 4; ++j)
        acc[i][j] = __builtin_amdgcn_mfma_f32_16x16x32_bf16(af[i], bfr[j], acc[i][j], 0, 0, 0);
  }

  #pragma unroll
  for (int j = 0; j < 4; ++j) {
    int col = n0 + j * 16 + r;
    #pragma unroll
    for (int i = 0; i < 4; ++i) {
      int row0 = m0 + i * 16 + q * 4;
      #pragma unroll
      for (int rr = 0; rr < 4; ++rr)
        C[(long)(row0 + rr) * ldc + col] = __float2bfloat16(acc[i][j][rr] * alpha);
    }
  }
}

// ---------------------------------------------------------------------------
// Fused fp32->bf16 converts for from/to (blockIdx.y selects). 4M elems each.
// ---------------------------------------------------------------------------
__global__ __launch_bounds__(256) void cvt2(
    const float* __restrict__ a, const float* __restrict__ b,
    bf16* __restrict__ oa, bf16* __restrict__ ob)
{
  const float* in = blockIdx.y ? b : a;
  bf16* out = blockIdx.y ? ob : oa;
  int i = (blockIdx.x * 256 + threadIdx.x) * 8;
  float4 v0 = *(const float4*)(in + i);
  float4 v1 = *(const float4*)(in + i + 4);
  uint4 pk;
  pk.x = pack2bf(v0.x, v0.y);
  pk.y = pack2bf(v0.z, v0.w);
  pk.z = pack2bf(v1.x, v1.y);
  pk.w = pack2bf(v1.z, v1.w);
  *(uint4*)(out + i) = pk;
}

// ---------------------------------------------------------------------------
// Fused 4-way weight transpose: fp32 [1024,1024] -> bf16 transposed, z=0..3.
// ---------------------------------------------------------------------------
struct WT4 { const float* s[4]; bf16* d[4]; };

__global__ __launch_bounds__(256) void wtrans4(WT4 a) {
  __shared__ bf16 tile[64][66];
  int z = blockIdx.z;
  const float* in = a.s[z];
  bf16* out = a.d[z];
  int r0 = blockIdx.x * 64, c0 = blockIdx.y * 64;
  int tx = threadIdx.x & 63, ty = threadIdx.x >> 6;
  #pragma unroll
  for (int i = 0; i < 16; ++i) {
    int rr = i * 4 + ty;
    tile[rr][tx] = __float2bfloat16(in[(long)(r0 + rr) * 1024 + c0 + tx]);
  }
  __syncthreads();
  #pragma unroll
  for (int i = 0; i < 16; ++i) {
    int rr = i * 4 + ty;
    out[(long)(c0 + rr) * 1024 + r0 + tx] = tile[tx][rr];
  }
}

// ---------------------------------------------------------------------------
// Batched 64x64-tiled bf16 transpose (V -> Vt).
// ---------------------------------------------------------------------------
__global__ __launch_bounds__(256) void transpose_bf16(
    const bf16* __restrict__ in, long i_bs1, long i_bs2, int i_rs,
    bf16* __restrict__ out, long o_bs1, long o_bs2, int o_rs, int Z2)
{
  __shared__ bf16 tile[64][66];
  int z = blockIdx.z, z1 = z / Z2, z2 = z - z1 * Z2;
  const bf16* ib = in + z1 * i_bs1 + z2 * i_bs2;
  bf16* ob = out + z1 * o_bs1 + z2 * o_bs2;
  int r0 = blockIdx.x * 64, c0 = blockIdx.y * 64;
  int tx = threadIdx.x & 63, ty = threadIdx.x >> 6;
  #pragma unroll
  for (int i = 0; i < 16; ++i) {
    int rr = i * 4 + ty;
    tile[rr][tx] = ib[(long)(r0 + rr) * i_rs + c0 + tx];
  }
  __syncthreads();
  #pragma unroll
  for (int i = 0; i < 16; ++i) {
    int rr = i * 4 + ty;
    ob[(long)(c0 + rr) * o_rs + r0 + tx] = tile[tx][rr];
  }
}

// ---------------------------------------------------------------------------
// Talking-heads core v2 (pre-mix + mask + softmax + post-mix), in-place.
// Block = (f, b); thread owns 4 contiguous t, all 16 heads in registers.
// __launch_bounds__(256,3): authorize ~170 VGPRs. Live set is ~150 (u[16]=32
// + mA/mB=64 + oA/oB=64); the default budget chose 96 VGPRs -> scratch
// spills -> 19.5% occupancy / VALUBusy capped at 51% (round-5 counters).
// ---------------------------------------------------------------------------
__global__ __launch_bounds__(256, 3) void mixsoftmax2(
    bf16* __restrict__ sc, long sc_bs, const float* __restrict__ pre,
    const float* __restrict__ post, const int* __restrict__ mask)
{
  __shared__ float wpre[256], wpost[256];
  __shared__ float zbuf[16][256];
  __shared__ float zbuf2[16][16];
  __shared__ float zinv[16];
  int tid = threadIdx.x;
  int f = blockIdx.x, b = blockIdx.y;
  wpre[tid] = pre[tid];
  wpost[tid] = post[tid];
  __syncthreads();

  unsigned short* scb = (unsigned short*)(sc + (long)b * sc_bs) + ((long)f << 10);
  const int* mk = mask + ((long)b << 20) + ((long)f << 10);
  int tg = tid * 4;

  // prefetch all 16 head-rows for this thread's 4 t's
  uint2 u[16];
  #pragma unroll
  for (int n = 0; n < 16; ++n)
    u[n] = *(const uint2*)(scb + ((long)n << 20) + tg);
  int4 mm = *(const int4*)(mk + tg);
  float madd0 = (1.0f - (float)mm.x) * -10000.0f;
  float madd1 = (1.0f - (float)mm.y) * -10000.0f;
  float madd2 = (1.0f - (float)mm.z) * -10000.0f;
  float madd3 = (1.0f - (float)mm.w) * -10000.0f;

  f32x2 mA[16], mB[16];
  #pragma unroll
  for (int l = 0; l < 16; ++l) {
    mA[l] = (f32x2){madd0, madd1};
    mB[l] = (f32x2){madd2, madd3};
  }

  // pre-mix: mA/mB[l] += s[n] * wpre[n][l]
  #pragma unroll
  for (int n = 0; n < 16; ++n) {
    unsigned lo = u[n].x, hi = u[n].y;
    f32x2 s01 = (f32x2){__uint_as_float((lo & 0xffffu) << 16),
                        __uint_as_float(lo & 0xffff0000u)};
    f32x2 s23 = (f32x2){__uint_as_float((hi & 0xffffu) << 16),
                        __uint_as_float(hi & 0xffff0000u)};
    const float4* wr = (const float4*)&wpre[n * 16];
    #pragma unroll
    for (int g = 0; g < 4; ++g) {
      float4 wv = wr[g];
      mA[g * 4 + 0] += s01 * wv.x;  mB[g * 4 + 0] += s23 * wv.x;
      mA[g * 4 + 1] += s01 * wv.y;  mB[g * 4 + 1] += s23 * wv.y;
      mA[g * 4 + 2] += s01 * wv.z;  mB[g * 4 + 2] += s23 * wv.z;
      mA[g * 4 + 3] += s01 * wv.w;  mB[g * 4 + 3] += s23 * wv.w;
    }
  }

  // exp (no max subtraction) + per-thread partial row-sums
  #pragma unroll
  for (int l = 0; l < 16; ++l) {
    mA[l].x = __expf(mA[l].x);  mA[l].y = __expf(mA[l].y);
    mB[l].x = __expf(mB[l].x);  mB[l].y = __expf(mB[l].y);
    zbuf[l][tid] = (mA[l].x + mA[l].y) + (mB[l].x + mB[l].y);
  }
  __syncthreads();
  {
    int l = tid >> 4, c = tid & 15;
    const float4* zr = (const float4*)&zbuf[l][c * 16];
    float4 a0 = zr[0], a1 = zr[1], a2 = zr[2], a3 = zr[3];
    zbuf2[l][c] = ((a0.x + a0.y) + (a0.z + a0.w)) + ((a1.x + a1.y) + (a1.z + a1.w)) +
                  ((a2.x + a2.y) + (a2.z + a2.w)) + ((a3.x + a3.y) + (a3.z + a3.w));
  }
  __syncthreads();
  if (tid < 16) {
    const float4* zr = (const float4*)&zbuf2[tid][0];
    float4 a0 = zr[0], a1 = zr[1], a2 = zr[2], a3 = zr[3];
    float s = ((a0.x + a0.y) + (a0.z + a0.w)) + ((a1.x + a1.y) + (a1.z + a1.w)) +
              ((a2.x + a2.y) + (a2.z + a2.w)) + ((a3.x + a3.y) + (a3.z + a3.w));
    zinv[tid] = 1.0f / s;
  }
  __syncthreads();

  // post-mix on normalized probs (straight from registers)
  f32x2 oA[16], oB[16];
  #pragma unroll
  for (int l = 0; l < 16; ++l) {
    oA[l] = (f32x2){0.f, 0.f};
    oB[l] = (f32x2){0.f, 0.f};
  }
  #pragma unroll
  for (int n = 0; n < 16; ++n) {
    float zi = zinv[n];
    f32x2 e01 = mA[n] * zi, e23 = mB[n] * zi;
    const float4* wr = (const float4*)&wpost[n * 16];
    #pragma unroll
    for (int g = 0; g < 4; ++g) {
      float4 wv = wr[g];
      oA[g * 4 + 0] += e01 * wv.x;  oB[g * 4 + 0] += e23 * wv.x;
      oA[g * 4 + 1] += e01 * wv.y;  oB[g * 4 + 1] += e23 * wv.y;
      oA[g * 4 + 2] += e01 * wv.z;  oB[g * 4 + 2] += e23 * wv.z;
      oA[g * 4 + 3] += e01 * wv.w;  oB[g * 4 + 3] += e23 * wv.w;
    }
  }
  #pragma unroll
  for (int l = 0; l < 16; ++l) {
    uint2 st;
    st.x = pack2bf(oA[l].x, oA[l].y);
    st.y = pack2bf(oB[l].x, oB[l].y);
    *(uint2*)(scb + ((long)l << 20) + tg) = st;
  }
}

// ---------------------------------------------------------------------------
// B=4, S=1024, D=1024, N=16, H=64. fp32 I/O, bf16 internal.
// ws (bf16 elems, M1=1<<20): big path 85M = 170 MB (Sc 64M overlapping the
// dead phase-1 staging), small path 37M = 74 MB (per-batch Sc 16M).
// ---------------------------------------------------------------------------
extern "C" void kernel_launch(void* const* d_in, const int* in_sizes, int n_in,
                              void* d_out, int out_size, void* d_ws, size_t ws_size,
                              hipStream_t stream) {
  const float* from = (const float*)d_in[0];
  const float* to   = (const float*)d_in[1];
  const int*  mask  = (const int*)d_in[2];
  const float* wq = (const float*)d_in[3];
  const float* bq = (const float*)d_in[4];
  const float* wk = (const float*)d_in[5];
  const float* bk = (const float*)d_in[6];
  const float* wv = (const float*)d_in[7];
  const float* bv = (const float*)d_in[8];
  const float* pre  = (const float*)d_in[9];
  const float* post = (const float*)d_in[10];
  const float* wo = (const float*)d_in[11];
  const float* bo = (const float*)d_in[12];
  float* out = (float*)d_out;

  bf16* W = (bf16*)d_ws;
  const long M1 = 1048576;
  bool big = ws_size >= (size_t)(85 * M1) * 2;

  bf16 *Sc, *fromB, *toB, *wqT, *wkT, *wvT, *woT, *Q, *Kp, *V, *Vt, *ctx;
  if (big) {
    Sc = W;                 fromB = W;            toB = W + 4 * M1;
    wqT = W + 8 * M1;       wkT = W + 9 * M1;     wvT = W + 10 * M1;
    woT = W + 64 * M1;      Q = W + 65 * M1;      Kp = W + 69 * M1;
    V = W + 73 * M1;        Vt = W + 77 * M1;     ctx = W + 81 * M1;
  } else {
    Sc = W;                 fromB = W;            toB = W + 4 * M1;
    wqT = W + 8 * M1;       wkT = W + 9 * M1;     wvT = W + 10 * M1;
    woT = W + 16 * M1;      Q = W + 17 * M1;      Kp = W + 21 * M1;
    V = W + 25 * M1;        Vt = W + 29 * M1;     ctx = W + 33 * M1;
  }

  dim3 blk(256);

  // 1) converts (1 dispatch) + weight transposes (1 dispatch)
  cvt2<<<dim3(2048, 2), blk, 0, stream>>>(from, to, fromB, toB);
  WT4 wt;
  wt.s[0] = wq; wt.s[1] = wk; wt.s[2] = wv; wt.s[3] = wo;
  wt.d[0] = wqT; wt.d[1] = wkT; wt.d[2] = wvT; wt.d[3] = woT;
  wtrans4<<<dim3(16, 16, 4), blk, 0, stream>>>(wt);

  // 2) QKV projections, z-batched (1 dispatch), 128x64 tiles (512 blocks/z)
  QKVArgs qa;
  qa.A[0] = fromB; qa.A[1] = toB; qa.A[2] = toB;
  qa.Bw[0] = wqT;  qa.Bw[1] = wkT; qa.Bw[2] = wvT;
  qa.C[0] = Q;     qa.C[1] = Kp;  qa.C[2] = V;
  qa.bias[0] = bq; qa.bias[1] = bk; qa.bias[2] = bv;
  gemm_qkv<<<dim3(32, 16, 3), blk, 0, stream>>>(qa);

  // 3) V [B,S,N,H] -> Vt [B,N,H,S]
  transpose_bf16<<<dim3(16, 1, 64), blk, 0, stream>>>(V, M1, 64, 1024,
                                                      Vt, M1, 65536, 1024, 16);

  if (big) {
    // 4) scores (direct K=64): z=(b,n): Sc[b,n] = 0.125*Q[b,:,n,:]@K[b,:,n,:]^T
    gemm_k64<<<dim3(8, 8, 64), blk, 0, stream>>>(
        Q, M1, 64, 1024, Kp, M1, 64, 1024, Sc, 16 * M1, M1, 1024, 16, 0.125f);
    // 5) talking-heads softmax
    mixsoftmax2<<<dim3(1024, 4), blk, 0, stream>>>(Sc, 16 * M1, pre, post, mask);
    // 6) PV: z=(b,l): ctx[b,:,l,:] = Sc[b,l]@Vt[b,l]^T
    gemm_lds64<<<dim3(8, 1, 64), blk, 0, stream>>>(
        Sc, 16 * M1, M1, 1024, Vt, M1, 65536, 1024, ctx, M1, 64, 1024, nullptr,
        1024, 16, 1.0f, 0);
  } else {
    for (int b = 0; b < 4; ++b) {
      gemm_k64<<<dim3(8, 8, 16), blk, 0, stream>>>(
          Q + b * M1, 0, 64, 1024, Kp + b * M1, 0, 64, 1024,
          Sc, 0, M1, 1024, 16, 0.125f);
      mixsoftmax2<<<dim3(1024, 1), blk, 0, stream>>>(Sc, 0, pre, post, mask + b * M1);
      gemm_lds64<<<dim3(8, 1, 16), blk, 0, stream>>>(
          Sc, 0, M1, 1024, Vt + b * M1, 0, 65536, 1024,
          ctx + b * M1, 0, 64, 1024, nullptr, 1024, 16, 1.0f, 0);
    }
  }

  // 7) out = ctx [4096,1024] @ woT^T + bo -> d_out (fp32)
  gemm_lds64<<<dim3(32, 16, 1), blk, 0, stream>>>(
      ctx, 0, 0, 1024, woT, 0, 0, 1024, out, 0, 0, 1024, bo, 1024, 1, 1.0f, 1);
}

// Round 8
// 347.415 us; speedup vs baseline: 1.0996x; 1.0487x over previous
//
#include <hip/hip_runtime.h>
#include <hip/hip_bf16.h>

typedef __hip_bfloat16 bf16;
using short8 = __attribute__((ext_vector_type(8))) short;
using f32x4  = __attribute__((ext_vector_type(4))) float;
using f32x2  = __attribute__((ext_vector_type(2))) float;

#ifndef __has_builtin
#define __has_builtin(x) 0
#endif
#if __has_builtin(__builtin_amdgcn_global_load_lds)
#define HAVE_GLL 1
#else
#define HAVE_GLL 0
#endif

__device__ inline void stage16(const short* __restrict__ g, short* l, int lane) {
#if HAVE_GLL
  __builtin_amdgcn_global_load_lds((__attribute__((address_space(1))) void*)g,
                                   (__attribute__((address_space(3))) void*)l,
                                   16, 0, 0);
#else
  *(short8*)(l + lane * 8) = *(const short8*)g;
#endif
}

__device__ inline unsigned pack2bf(float a, float b) {
  bf16 h0 = __float2bfloat16(a), h1 = __float2bfloat16(b);
  return (unsigned)*(unsigned short*)&h0 | ((unsigned)*(unsigned short*)&h1 << 16);
}

// ---------------------------------------------------------------------------
// LDS-staged batched GEMM, tile 128x64, BK=64 (m97 structure). C = alpha*A@B^T
// (+bias). A:[M,K](lda) bf16, B:[N,K](ldb) bf16, C bf16 or fp32.
// ---------------------------------------------------------------------------
__global__ __launch_bounds__(256) void gemm_lds64(
    const bf16* __restrict__ Ag, long a_bs1, long a_bs2, int lda,
    const bf16* __restrict__ Bg, long b_bs1, long b_bs2, int ldb,
    void* __restrict__ Cg, long c_bs1, long c_bs2, int ldc,
    const float* __restrict__ bias, int K, int Z2, float alpha, int cf32)
{
  __shared__ short As[128 * 64];
  __shared__ short Bs[64 * 64];

  int z = blockIdx.z, z1 = z / Z2, z2 = z - z1 * Z2;
  const short* A = (const short*)(Ag + z1 * a_bs1 + z2 * a_bs2);
  const short* B = (const short*)(Bg + z1 * b_bs1 + z2 * b_bs2);

  int tid = threadIdx.x, lane = tid & 63, w = tid >> 6;
  int wm = w & 1, wn = w >> 1;
  int m0 = blockIdx.x * 128, n0 = blockIdx.y * 64;
  int r = lane & 15, q = lane >> 4;

  int srow = lane >> 3, scol = (lane & 7) * 8;
  const short* Asrc = A + (long)(m0 + w * 32 + srow) * lda + scol;
  const short* Bsrc = B + (long)(n0 + w * 16 + srow) * ldb + scol;
  short* Adst = As + (w * 32) * 64;
  short* Bdst = Bs + (w * 16) * 64;

  f32x4 acc[4][2];
  #pragma unroll
  for (int i = 0; i < 4; ++i)
    #pragma unroll
    for (int j = 0; j < 2; ++j) acc[i][j] = (f32x4){0.f, 0.f, 0.f, 0.f};

  for (int kt = 0; kt < K; kt += 64) {
    #pragma unroll
    for (int i = 0; i < 4; ++i)
      stage16(Asrc + (long)i * 8 * lda + kt, Adst + i * 8 * 64, lane);
    #pragma unroll
    for (int i = 0; i < 2; ++i)
      stage16(Bsrc + (long)i * 8 * ldb + kt, Bdst + i * 8 * 64, lane);
    __syncthreads();
    #pragma unroll
    for (int kk = 0; kk < 64; kk += 32) {
      short8 af[4], bfr[2];
      #pragma unroll
      for (int i = 0; i < 4; ++i)
        af[i] = *(const short8*)&As[(wm * 64 + i * 16 + r) * 64 + kk + q * 8];
      #pragma unroll
      for (int j = 0; j < 2; ++j)
        bfr[j] = *(const short8*)&Bs[(wn * 32 + j * 16 + r) * 64 + kk + q * 8];
      #pragma unroll
      for (int i = 0; i < 4; ++i)
        #pragma unroll
        for (int j = 0; j < 2; ++j)
          acc[i][j] = __builtin_amdgcn_mfma_f32_16x16x32_bf16(af[i], bfr[j], acc[i][j], 0, 0, 0);
    }
    __syncthreads();
  }

  long cb = z1 * c_bs1 + z2 * c_bs2;
  #pragma unroll
  for (int j = 0; j < 2; ++j) {
    int col = n0 + wn * 32 + j * 16 + r;
    float bv = bias ? bias[col] : 0.0f;
    #pragma unroll
    for (int i = 0; i < 4; ++i) {
      int row0 = m0 + wm * 64 + i * 16 + q * 4;
      #pragma unroll
      for (int rr = 0; rr < 4; ++rr) {
        float val = acc[i][j][rr] * alpha + bv;
        long idx = cb + (long)(row0 + rr) * ldc + col;
        if (cf32) ((float*)Cg)[idx] = val;
        else ((bf16*)Cg)[idx] = __float2bfloat16(val);
      }
    }
  }
}

// ---------------------------------------------------------------------------
// Fused z-batched QKV projection: z=0,1,2 -> Q,K,V. gemm_lds64 body,
// M=4096, N=1024, K=1024, ld*=1024.
// ---------------------------------------------------------------------------
struct QKVArgs {
  const bf16* A[3];
  const bf16* Bw[3];
  bf16* C[3];
  const float* bias[3];
};

__global__ __launch_bounds__(256) void gemm_qkv(QKVArgs args) {
  __shared__ short As[128 * 64];
  __shared__ short Bs[64 * 64];

  int z = blockIdx.z;
  const short* A = (const short*)args.A[z];
  const short* B = (const short*)args.Bw[z];
  bf16* C = args.C[z];
  const float* bias = args.bias[z];

  int tid = threadIdx.x, lane = tid & 63, w = tid >> 6;
  int wm = w & 1, wn = w >> 1;
  int m0 = blockIdx.x * 128, n0 = blockIdx.y * 64;
  int r = lane & 15, q = lane >> 4;

  int srow = lane >> 3, scol = (lane & 7) * 8;
  const short* Asrc = A + (long)(m0 + w * 32 + srow) * 1024 + scol;
  const short* Bsrc = B + (long)(n0 + w * 16 + srow) * 1024 + scol;
  short* Adst = As + (w * 32) * 64;
  short* Bdst = Bs + (w * 16) * 64;

  f32x4 acc[4][2];
  #pragma unroll
  for (int i = 0; i < 4; ++i)
    #pragma unroll
    for (int j = 0; j < 2; ++j) acc[i][j] = (f32x4){0.f, 0.f, 0.f, 0.f};

  for (int kt = 0; kt < 1024; kt += 64) {
    #pragma unroll
    for (int i = 0; i < 4; ++i)
      stage16(Asrc + (long)i * 8 * 1024 + kt, Adst + i * 8 * 64, lane);
    #pragma unroll
    for (int i = 0; i < 2; ++i)
      stage16(Bsrc + (long)i * 8 * 1024 + kt, Bdst + i * 8 * 64, lane);
    __syncthreads();
    #pragma unroll
    for (int kk = 0; kk < 64; kk += 32) {
      short8 af[4], bfr[2];
      #pragma unroll
      for (int i = 0; i < 4; ++i)
        af[i] = *(const short8*)&As[(wm * 64 + i * 16 + r) * 64 + kk + q * 8];
      #pragma unroll
      for (int j = 0; j < 2; ++j)
        bfr[j] = *(const short8*)&Bs[(wn * 32 + j * 16 + r) * 64 + kk + q * 8];
      #pragma unroll
      for (int i = 0; i < 4; ++i)
        #pragma unroll
        for (int j = 0; j < 2; ++j)
          acc[i][j] = __builtin_amdgcn_mfma_f32_16x16x32_bf16(af[i], bfr[j], acc[i][j], 0, 0, 0);
    }
    __syncthreads();
  }

  #pragma unroll
  for (int j = 0; j < 2; ++j) {
    int col = n0 + wn * 32 + j * 16 + r;
    float bv = bias[col];
    #pragma unroll
    for (int i = 0; i < 4; ++i) {
      int row0 = m0 + wm * 64 + i * 16 + q * 4;
      #pragma unroll
      for (int rr = 0; rr < 4; ++rr)
        C[(long)(row0 + rr) * 1024 + col] = __float2bfloat16(acc[i][j][rr] + bv);
    }
  }
}

// ---------------------------------------------------------------------------
// Direct (no-LDS) K=64 batched GEMM for scores: tile 128x128, wave 64x64.
// ---------------------------------------------------------------------------
__global__ __launch_bounds__(256) void gemm_k64(
    const bf16* __restrict__ Ag, long a_bs1, long a_bs2, int lda,
    const bf16* __restrict__ Bg, long b_bs1, long b_bs2, int ldb,
    bf16* __restrict__ Cg, long c_bs1, long c_bs2, int ldc,
    int Z2, float alpha)
{
  int z = blockIdx.z, z1 = z / Z2, z2 = z - z1 * Z2;
  const short* A = (const short*)(Ag + z1 * a_bs1 + z2 * a_bs2);
  const short* B = (const short*)(Bg + z1 * b_bs1 + z2 * b_bs2);
  bf16* C = Cg + z1 * c_bs1 + z2 * c_bs2;

  int tid = threadIdx.x, lane = tid & 63, w = tid >> 6;
  int wm = w & 1, wn = w >> 1;
  int m0 = blockIdx.x * 128 + wm * 64;
  int n0 = blockIdx.y * 128 + wn * 64;
  int r = lane & 15, q = lane >> 4;

  const short* Ar = A + (long)(m0 + r) * lda + q * 8;
  const short* Br = B + (long)(n0 + r) * ldb + q * 8;

  f32x4 acc[4][4];
  #pragma unroll
  for (int i = 0; i < 4; ++i)
    #pragma unroll
    for (int j = 0; j < 4; ++j) acc[i][j] = (f32x4){0.f, 0.f, 0.f, 0.f};

  #pragma unroll
  for (int kk = 0; kk < 64; kk += 32) {
    short8 af[4], bfr[4];
    #pragma unroll
    for (int i = 0; i < 4; ++i) af[i] = *(const short8*)(Ar + (long)i * 16 * lda + kk);
    #pragma unroll
    for (int j = 0; j < 4; ++j) bfr[j] = *(const short8*)(Br + (long)j * 16 * ldb + kk);
    #pragma unroll
    for (int i = 0; i < 4; ++i)
      #pragma unroll
      for (int j = 0; j < 4; ++j)
        acc[i][j] = __builtin_amdgcn_mfma_f32_16x16x32_bf16(af[i], bfr[j], acc[i][j], 0, 0, 0);
  }

  #pragma unroll
  for (int j = 0; j < 4; ++j) {
    int col = n0 + j * 16 + r;
    #pragma unroll
    for (int i = 0; i < 4; ++i) {
      int row0 = m0 + i * 16 + q * 4;
      #pragma unroll
      for (int rr = 0; rr < 4; ++rr)
        C[(long)(row0 + rr) * ldc + col] = __float2bfloat16(acc[i][j][rr] * alpha);
    }
  }
}

// ---------------------------------------------------------------------------
// Fused fp32->bf16 converts for from/to (blockIdx.y selects). 4M elems each.
// ---------------------------------------------------------------------------
__global__ __launch_bounds__(256) void cvt2(
    const float* __restrict__ a, const float* __restrict__ b,
    bf16* __restrict__ oa, bf16* __restrict__ ob)
{
  const float* in = blockIdx.y ? b : a;
  bf16* out = blockIdx.y ? ob : oa;
  int i = (blockIdx.x * 256 + threadIdx.x) * 8;
  float4 v0 = *(const float4*)(in + i);
  float4 v1 = *(const float4*)(in + i + 4);
  uint4 pk;
  pk.x = pack2bf(v0.x, v0.y);
  pk.y = pack2bf(v0.z, v0.w);
  pk.z = pack2bf(v1.x, v1.y);
  pk.w = pack2bf(v1.z, v1.w);
  *(uint4*)(out + i) = pk;
}

// ---------------------------------------------------------------------------
// Fused 4-way weight transpose: fp32 [1024,1024] -> bf16 transposed, z=0..3.
// ---------------------------------------------------------------------------
struct WT4 { const float* s[4]; bf16* d[4]; };

__global__ __launch_bounds__(256) void wtrans4(WT4 a) {
  __shared__ bf16 tile[64][66];
  int z = blockIdx.z;
  const float* in = a.s[z];
  bf16* out = a.d[z];
  int r0 = blockIdx.x * 64, c0 = blockIdx.y * 64;
  int tx = threadIdx.x & 63, ty = threadIdx.x >> 6;
  #pragma unroll
  for (int i = 0; i < 16; ++i) {
    int rr = i * 4 + ty;
    tile[rr][tx] = __float2bfloat16(in[(long)(r0 + rr) * 1024 + c0 + tx]);
  }
  __syncthreads();
  #pragma unroll
  for (int i = 0; i < 16; ++i) {
    int rr = i * 4 + ty;
    out[(long)(c0 + rr) * 1024 + r0 + tx] = tile[tx][rr];
  }
}

// ---------------------------------------------------------------------------
// Batched 64x64-tiled bf16 transpose (V -> Vt).
// ---------------------------------------------------------------------------
__global__ __launch_bounds__(256) void transpose_bf16(
    const bf16* __restrict__ in, long i_bs1, long i_bs2, int i_rs,
    bf16* __restrict__ out, long o_bs1, long o_bs2, int o_rs, int Z2)
{
  __shared__ bf16 tile[64][66];
  int z = blockIdx.z, z1 = z / Z2, z2 = z - z1 * Z2;
  const bf16* ib = in + z1 * i_bs1 + z2 * i_bs2;
  bf16* ob = out + z1 * o_bs1 + z2 * o_bs2;
  int r0 = blockIdx.x * 64, c0 = blockIdx.y * 64;
  int tx = threadIdx.x & 63, ty = threadIdx.x >> 6;
  #pragma unroll
  for (int i = 0; i < 16; ++i) {
    int rr = i * 4 + ty;
    tile[rr][tx] = ib[(long)(r0 + rr) * i_rs + c0 + tx];
  }
  __syncthreads();
  #pragma unroll
  for (int i = 0; i < 16; ++i) {
    int rr = i * 4 + ty;
    ob[(long)(c0 + rr) * o_rs + r0 + tx] = tile[tx][rr];
  }
}

// ---------------------------------------------------------------------------
// Talking-heads core v4 (pre-mix + mask + softmax + post-mix), in-place.
// Block = (f, b), 512 threads spanning all 1024 t; thread owns 2 contiguous
// t, all 16 heads in registers. vs v2 (4 t/thread): live set halves to ~80
// VGPRs (u=16, mA=32, oA=32 regs), so waves stay resident without spills —
// round-5 v2 was latency-bound at 19.5% occupancy with a ~160-float live set.
// ---------------------------------------------------------------------------
__global__ __launch_bounds__(512) void mixsoftmax4(
    bf16* __restrict__ sc, long sc_bs, const float* __restrict__ pre,
    const float* __restrict__ post, const int* __restrict__ mask)
{
  __shared__ float wpre[256], wpost[256];
  __shared__ float zbuf[16][512];
  __shared__ float zbuf2[16][32];
  __shared__ float zinv[16];
  int tid = threadIdx.x;
  int f = blockIdx.x, b = blockIdx.y;
  if (tid < 256) {
    wpre[tid] = pre[tid];
    wpost[tid] = post[tid];
  }
  __syncthreads();

  unsigned short* scb = (unsigned short*)(sc + (long)b * sc_bs) + ((long)f << 10);
  const int* mk = mask + ((long)b << 20) + ((long)f << 10);
  int tg = tid * 2;

  // prefetch all 16 head-rows for this thread's 2 t's (4B each, coalesced)
  unsigned u[16];
  #pragma unroll
  for (int n = 0; n < 16; ++n)
    u[n] = *(const unsigned*)(scb + ((long)n << 20) + tg);
  int2 mm = *(const int2*)(mk + tg);
  float madd0 = (1.0f - (float)mm.x) * -10000.0f;
  float madd1 = (1.0f - (float)mm.y) * -10000.0f;

  f32x2 mA[16];
  #pragma unroll
  for (int l = 0; l < 16; ++l) mA[l] = (f32x2){madd0, madd1};

  // pre-mix: mA[l] += s[n] * wpre[n][l]
  #pragma unroll
  for (int n = 0; n < 16; ++n) {
    unsigned lo = u[n];
    f32x2 s01 = (f32x2){__uint_as_float((lo & 0xffffu) << 16),
                        __uint_as_float(lo & 0xffff0000u)};
    const float4* wr = (const float4*)&wpre[n * 16];
    #pragma unroll
    for (int g = 0; g < 4; ++g) {
      float4 wv = wr[g];
      mA[g * 4 + 0] += s01 * wv.x;
      mA[g * 4 + 1] += s01 * wv.y;
      mA[g * 4 + 2] += s01 * wv.z;
      mA[g * 4 + 3] += s01 * wv.w;
    }
  }

  // exp (no max subtraction: |mixed| ~ O(1), masked -> underflow to 0)
  #pragma unroll
  for (int l = 0; l < 16; ++l) {
    mA[l].x = __expf(mA[l].x);
    mA[l].y = __expf(mA[l].y);
    zbuf[l][tid] = mA[l].x + mA[l].y;
  }
  __syncthreads();
  {
    int l = tid >> 5, c = tid & 31;   // 16 l x 32 chunks of 16
    const float4* zr = (const float4*)&zbuf[l][c * 16];
    float4 a0 = zr[0], a1 = zr[1], a2 = zr[2], a3 = zr[3];
    zbuf2[l][c] = ((a0.x + a0.y) + (a0.z + a0.w)) + ((a1.x + a1.y) + (a1.z + a1.w)) +
                  ((a2.x + a2.y) + (a2.z + a2.w)) + ((a3.x + a3.y) + (a3.z + a3.w));
  }
  __syncthreads();
  if (tid < 16) {
    const float4* zr = (const float4*)&zbuf2[tid][0];
    float s = 0.0f;
    #pragma unroll
    for (int g = 0; g < 8; ++g) {
      float4 a0 = zr[g];
      s += (a0.x + a0.y) + (a0.z + a0.w);
    }
    zinv[tid] = 1.0f / s;
  }
  __syncthreads();

  // post-mix on normalized probs (straight from registers)
  f32x2 oA[16];
  #pragma unroll
  for (int l = 0; l < 16; ++l) oA[l] = (f32x2){0.f, 0.f};
  #pragma unroll
  for (int n = 0; n < 16; ++n) {
    f32x2 e01 = mA[n] * zinv[n];
    const float4* wr = (const float4*)&wpost[n * 16];
    #pragma unroll
    for (int g = 0; g < 4; ++g) {
      float4 wv = wr[g];
      oA[g * 4 + 0] += e01 * wv.x;
      oA[g * 4 + 1] += e01 * wv.y;
      oA[g * 4 + 2] += e01 * wv.z;
      oA[g * 4 + 3] += e01 * wv.w;
    }
  }
  #pragma unroll
  for (int l = 0; l < 16; ++l)
    *(unsigned*)(scb + ((long)l << 20) + tg) = pack2bf(oA[l].x, oA[l].y);
}

// ---------------------------------------------------------------------------
// B=4, S=1024, D=1024, N=16, H=64. fp32 I/O, bf16 internal.
// ws (bf16 elems, M1=1<<20): big path 85M = 170 MB (Sc 64M overlapping the
// dead phase-1 staging), small path 37M = 74 MB (per-batch Sc 16M).
// ---------------------------------------------------------------------------
extern "C" void kernel_launch(void* const* d_in, const int* in_sizes, int n_in,
                              void* d_out, int out_size, void* d_ws, size_t ws_size,
                              hipStream_t stream) {
  const float* from = (const float*)d_in[0];
  const float* to   = (const float*)d_in[1];
  const int*  mask  = (const int*)d_in[2];
  const float* wq = (const float*)d_in[3];
  const float* bq = (const float*)d_in[4];
  const float* wk = (const float*)d_in[5];
  const float* bk = (const float*)d_in[6];
  const float* wv = (const float*)d_in[7];
  const float* bv = (const float*)d_in[8];
  const float* pre  = (const float*)d_in[9];
  const float* post = (const float*)d_in[10];
  const float* wo = (const float*)d_in[11];
  const float* bo = (const float*)d_in[12];
  float* out = (float*)d_out;

  bf16* W = (bf16*)d_ws;
  const long M1 = 1048576;
  bool big = ws_size >= (size_t)(85 * M1) * 2;

  bf16 *Sc, *fromB, *toB, *wqT, *wkT, *wvT, *woT, *Q, *Kp, *V, *Vt, *ctx;
  if (big) {
    Sc = W;                 fromB = W;            toB = W + 4 * M1;
    wqT = W + 8 * M1;       wkT = W + 9 * M1;     wvT = W + 10 * M1;
    woT = W + 64 * M1;      Q = W + 65 * M1;      Kp = W + 69 * M1;
    V = W + 73 * M1;        Vt = W + 77 * M1;     ctx = W + 81 * M1;
  } else {
    Sc = W;                 fromB = W;            toB = W + 4 * M1;
    wqT = W + 8 * M1;       wkT = W + 9 * M1;     wvT = W + 10 * M1;
    woT = W + 16 * M1;      Q = W + 17 * M1;      Kp = W + 21 * M1;
    V = W + 25 * M1;        Vt = W + 29 * M1;     ctx = W + 33 * M1;
  }

  dim3 blk(256);

  // 1) converts (1 dispatch) + weight transposes (1 dispatch)
  cvt2<<<dim3(2048, 2), blk, 0, stream>>>(from, to, fromB, toB);
  WT4 wt;
  wt.s[0] = wq; wt.s[1] = wk; wt.s[2] = wv; wt.s[3] = wo;
  wt.d[0] = wqT; wt.d[1] = wkT; wt.d[2] = wvT; wt.d[3] = woT;
  wtrans4<<<dim3(16, 16, 4), blk, 0, stream>>>(wt);

  // 2) QKV projections, z-batched (1 dispatch), 128x64 tiles (512 blocks/z)
  QKVArgs qa;
  qa.A[0] = fromB; qa.A[1] = toB; qa.A[2] = toB;
  qa.Bw[0] = wqT;  qa.Bw[1] = wkT; qa.Bw[2] = wvT;
  qa.C[0] = Q;     qa.C[1] = Kp;  qa.C[2] = V;
  qa.bias[0] = bq; qa.bias[1] = bk; qa.bias[2] = bv;
  gemm_qkv<<<dim3(32, 16, 3), blk, 0, stream>>>(qa);

  // 3) V [B,S,N,H] -> Vt [B,N,H,S]
  transpose_bf16<<<dim3(16, 1, 64), blk, 0, stream>>>(V, M1, 64, 1024,
                                                      Vt, M1, 65536, 1024, 16);

  if (big) {
    // 4) scores (direct K=64): z=(b,n): Sc[b,n] = 0.125*Q[b,:,n,:]@K[b,:,n,:]^T
    gemm_k64<<<dim3(8, 8, 64), blk, 0, stream>>>(
        Q, M1, 64, 1024, Kp, M1, 64, 1024, Sc, 16 * M1, M1, 1024, 16, 0.125f);
    // 5) talking-heads softmax (512-thread, 2 t/thread)
    mixsoftmax4<<<dim3(1024, 4), dim3(512), 0, stream>>>(Sc, 16 * M1, pre, post, mask);
    // 6) PV: z=(b,l): ctx[b,:,l,:] = Sc[b,l]@Vt[b,l]^T
    gemm_lds64<<<dim3(8, 1, 64), blk, 0, stream>>>(
        Sc, 16 * M1, M1, 1024, Vt, M1, 65536, 1024, ctx, M1, 64, 1024, nullptr,
        1024, 16, 1.0f, 0);
  } else {
    for (int b = 0; b < 4; ++b) {
      gemm_k64<<<dim3(8, 8, 16), blk, 0, stream>>>(
          Q + b * M1, 0, 64, 1024, Kp + b * M1, 0, 64, 1024,
          Sc, 0, M1, 1024, 16, 0.125f);
      mixsoftmax4<<<dim3(1024, 1), dim3(512), 0, stream>>>(Sc, 0, pre, post, mask + b * M1);
      gemm_lds64<<<dim3(8, 1, 16), blk, 0, stream>>>(
          Sc, 0, M1, 1024, Vt + b * M1, 0, 65536, 1024,
          ctx + b * M1, 0, 64, 1024, nullptr, 1024, 16, 1.0f, 0);
    }
  }

  // 7) out = ctx [4096,1024] @ woT^T + bo -> d_out (fp32)
  gemm_lds64<<<dim3(32, 16, 1), blk, 0, stream>>>(
      ctx, 0, 0, 1024, woT, 0, 0, 1024, out, 0, 0, 1024, bo, 1024, 1, 1.0f, 1);
}

// Round 9
// 344.597 us; speedup vs baseline: 1.1086x; 1.0082x over previous
//
#include <hip/hip_runtime.h>
#include <hip/hip_bf16.h>

typedef __hip_bfloat16 bf16;
using short8 = __attribute__((ext_vector_type(8))) short;
using f32x4  = __attribute__((ext_vector_type(4))) float;
using f32x2  = __attribute__((ext_vector_type(2))) float;

#ifndef __has_builtin
#define __has_builtin(x) 0
#endif
#if __has_builtin(__builtin_amdgcn_global_load_lds)
#define HAVE_GLL 1
#else
#define HAVE_GLL 0
#endif

__device__ inline void stage16(const short* __restrict__ g, short* l, int lane) {
#if HAVE_GLL
  __builtin_amdgcn_global_load_lds((__attribute__((address_space(1))) void*)g,
                                   (__attribute__((address_space(3))) void*)l,
                                   16, 0, 0);
#else
  *(short8*)(l + lane * 8) = *(const short8*)g;
#endif
}

__device__ inline unsigned pack2bf(float a, float b) {
  bf16 h0 = __float2bfloat16(a), h1 = __float2bfloat16(b);
  return (unsigned)*(unsigned short*)&h0 | ((unsigned)*(unsigned short*)&h1 << 16);
}

// Guaranteed packed fp32 FMA (2 FMA/lane/instr). All operands natural pairs.
__device__ inline f32x2 pk_fma(f32x2 a, f32x2 b, f32x2 c) {
#if defined(__gfx950__)
  f32x2 d;
  asm("v_pk_fma_f32 %0, %1, %2, %3" : "=v"(d) : "v"(a), "v"(b), "v"(c));
  return d;
#else
  return a * b + c;
#endif
}

__device__ inline f32x2 splat2(float s) { return (f32x2){s, s}; }

// ---------------------------------------------------------------------------
// LDS-staged batched GEMM, tile 128x64, BK=64 (m97 structure). C = alpha*A@B^T
// (+bias). A:[M,K](lda) bf16, B:[N,K](ldb) bf16, C bf16 or fp32.
// ---------------------------------------------------------------------------
__global__ __launch_bounds__(256) void gemm_lds64(
    const bf16* __restrict__ Ag, long a_bs1, long a_bs2, int lda,
    const bf16* __restrict__ Bg, long b_bs1, long b_bs2, int ldb,
    void* __restrict__ Cg, long c_bs1, long c_bs2, int ldc,
    const float* __restrict__ bias, int K, int Z2, float alpha, int cf32)
{
  __shared__ short As[128 * 64];
  __shared__ short Bs[64 * 64];

  int z = blockIdx.z, z1 = z / Z2, z2 = z - z1 * Z2;
  const short* A = (const short*)(Ag + z1 * a_bs1 + z2 * a_bs2);
  const short* B = (const short*)(Bg + z1 * b_bs1 + z2 * b_bs2);

  int tid = threadIdx.x, lane = tid & 63, w = tid >> 6;
  int wm = w & 1, wn = w >> 1;
  int m0 = blockIdx.x * 128, n0 = blockIdx.y * 64;
  int r = lane & 15, q = lane >> 4;

  int srow = lane >> 3, scol = (lane & 7) * 8;
  const short* Asrc = A + (long)(m0 + w * 32 + srow) * lda + scol;
  const short* Bsrc = B + (long)(n0 + w * 16 + srow) * ldb + scol;
  short* Adst = As + (w * 32) * 64;
  short* Bdst = Bs + (w * 16) * 64;

  f32x4 acc[4][2];
  #pragma unroll
  for (int i = 0; i < 4; ++i)
    #pragma unroll
    for (int j = 0; j < 2; ++j) acc[i][j] = (f32x4){0.f, 0.f, 0.f, 0.f};

  for (int kt = 0; kt < K; kt += 64) {
    #pragma unroll
    for (int i = 0; i < 4; ++i)
      stage16(Asrc + (long)i * 8 * lda + kt, Adst + i * 8 * 64, lane);
    #pragma unroll
    for (int i = 0; i < 2; ++i)
      stage16(Bsrc + (long)i * 8 * ldb + kt, Bdst + i * 8 * 64, lane);
    __syncthreads();
    #pragma unroll
    for (int kk = 0; kk < 64; kk += 32) {
      short8 af[4], bfr[2];
      #pragma unroll
      for (int i = 0; i < 4; ++i)
        af[i] = *(const short8*)&As[(wm * 64 + i * 16 + r) * 64 + kk + q * 8];
      #pragma unroll
      for (int j = 0; j < 2; ++j)
        bfr[j] = *(const short8*)&Bs[(wn * 32 + j * 16 + r) * 64 + kk + q * 8];
      #pragma unroll
      for (int i = 0; i < 4; ++i)
        #pragma unroll
        for (int j = 0; j < 2; ++j)
          acc[i][j] = __builtin_amdgcn_mfma_f32_16x16x32_bf16(af[i], bfr[j], acc[i][j], 0, 0, 0);
    }
    __syncthreads();
  }

  long cb = z1 * c_bs1 + z2 * c_bs2;
  #pragma unroll
  for (int j = 0; j < 2; ++j) {
    int col = n0 + wn * 32 + j * 16 + r;
    float bv = bias ? bias[col] : 0.0f;
    #pragma unroll
    for (int i = 0; i < 4; ++i) {
      int row0 = m0 + wm * 64 + i * 16 + q * 4;
      #pragma unroll
      for (int rr = 0; rr < 4; ++rr) {
        float val = acc[i][j][rr] * alpha + bv;
        long idx = cb + (long)(row0 + rr) * ldc + col;
        if (cf32) ((float*)Cg)[idx] = val;
        else ((bf16*)Cg)[idx] = __float2bfloat16(val);
      }
    }
  }
}

// ---------------------------------------------------------------------------
// Fused z-batched QKV projection: z=0,1,2 -> Q,K,V. gemm_lds64 body,
// M=4096, N=1024, K=1024, ld*=1024.
// ---------------------------------------------------------------------------
struct QKVArgs {
  const bf16* A[3];
  const bf16* Bw[3];
  bf16* C[3];
  const float* bias[3];
};

__global__ __launch_bounds__(256) void gemm_qkv(QKVArgs args) {
  __shared__ short As[128 * 64];
  __shared__ short Bs[64 * 64];

  int z = blockIdx.z;
  const short* A = (const short*)args.A[z];
  const short* B = (const short*)args.Bw[z];
  bf16* C = args.C[z];
  const float* bias = args.bias[z];

  int tid = threadIdx.x, lane = tid & 63, w = tid >> 6;
  int wm = w & 1, wn = w >> 1;
  int m0 = blockIdx.x * 128, n0 = blockIdx.y * 64;
  int r = lane & 15, q = lane >> 4;

  int srow = lane >> 3, scol = (lane & 7) * 8;
  const short* Asrc = A + (long)(m0 + w * 32 + srow) * 1024 + scol;
  const short* Bsrc = B + (long)(n0 + w * 16 + srow) * 1024 + scol;
  short* Adst = As + (w * 32) * 64;
  short* Bdst = Bs + (w * 16) * 64;

  f32x4 acc[4][2];
  #pragma unroll
  for (int i = 0; i < 4; ++i)
    #pragma unroll
    for (int j = 0; j < 2; ++j) acc[i][j] = (f32x4){0.f, 0.f, 0.f, 0.f};

  for (int kt = 0; kt < 1024; kt += 64) {
    #pragma unroll
    for (int i = 0; i < 4; ++i)
      stage16(Asrc + (long)i * 8 * 1024 + kt, Adst + i * 8 * 64, lane);
    #pragma unroll
    for (int i = 0; i < 2; ++i)
      stage16(Bsrc + (long)i * 8 * 1024 + kt, Bdst + i * 8 * 64, lane);
    __syncthreads();
    #pragma unroll
    for (int kk = 0; kk < 64; kk += 32) {
      short8 af[4], bfr[2];
      #pragma unroll
      for (int i = 0; i < 4; ++i)
        af[i] = *(const short8*)&As[(wm * 64 + i * 16 + r) * 64 + kk + q * 8];
      #pragma unroll
      for (int j = 0; j < 2; ++j)
        bfr[j] = *(const short8*)&Bs[(wn * 32 + j * 16 + r) * 64 + kk + q * 8];
      #pragma unroll
      for (int i = 0; i < 4; ++i)
        #pragma unroll
        for (int j = 0; j < 2; ++j)
          acc[i][j] = __builtin_amdgcn_mfma_f32_16x16x32_bf16(af[i], bfr[j], acc[i][j], 0, 0, 0);
    }
    __syncthreads();
  }

  #pragma unroll
  for (int j = 0; j < 2; ++j) {
    int col = n0 + wn * 32 + j * 16 + r;
    float bv = bias[col];
    #pragma unroll
    for (int i = 0; i < 4; ++i) {
      int row0 = m0 + wm * 64 + i * 16 + q * 4;
      #pragma unroll
      for (int rr = 0; rr < 4; ++rr)
        C[(long)(row0 + rr) * 1024 + col] = __float2bfloat16(acc[i][j][rr] + bv);
    }
  }
}

// ---------------------------------------------------------------------------
// Direct (no-LDS) K=64 batched GEMM for scores: tile 128x128, wave 64x64.
// ---------------------------------------------------------------------------
__global__ __launch_bounds__(256) void gemm_k64(
    const bf16* __restrict__ Ag, long a_bs1, long a_bs2, int lda,
    const bf16* __restrict__ Bg, long b_bs1, long b_bs2, int ldb,
    bf16* __restrict__ Cg, long c_bs1, long c_bs2, int ldc,
    int Z2, float alpha)
{
  int z = blockIdx.z, z1 = z / Z2, z2 = z - z1 * Z2;
  const short* A = (const short*)(Ag + z1 * a_bs1 + z2 * a_bs2);
  const short* B = (const short*)(Bg + z1 * b_bs1 + z2 * b_bs2);
  bf16* C = Cg + z1 * c_bs1 + z2 * c_bs2;

  int tid = threadIdx.x, lane = tid & 63, w = tid >> 6;
  int wm = w & 1, wn = w >> 1;
  int m0 = blockIdx.x * 128 + wm * 64;
  int n0 = blockIdx.y * 128 + wn * 64;
  int r = lane & 15, q = lane >> 4;

  const short* Ar = A + (long)(m0 + r) * lda + q * 8;
  const short* Br = B + (long)(n0 + r) * ldb + q * 8;

  f32x4 acc[4][4];
  #pragma unroll
  for (int i = 0; i < 4; ++i)
    #pragma unroll
    for (int j = 0; j < 4; ++j) acc[i][j] = (f32x4){0.f, 0.f, 0.f, 0.f};

  #pragma unroll
  for (int kk = 0; kk < 64; kk += 32) {
    short8 af[4], bfr[4];
    #pragma unroll
    for (int i = 0; i < 4; ++i) af[i] = *(const short8*)(Ar + (long)i * 16 * lda + kk);
    #pragma unroll
    for (int j = 0; j < 4; ++j) bfr[j] = *(const short8*)(Br + (long)j * 16 * ldb + kk);
    #pragma unroll
    for (int i = 0; i < 4; ++i)
      #pragma unroll
      for (int j = 0; j < 4; ++j)
        acc[i][j] = __builtin_amdgcn_mfma_f32_16x16x32_bf16(af[i], bfr[j], acc[i][j], 0, 0, 0);
  }

  #pragma unroll
  for (int j = 0; j < 4; ++j) {
    int col = n0 + j * 16 + r;
    #pragma unroll
    for (int i = 0; i < 4; ++i) {
      int row0 = m0 + i * 16 + q * 4;
      #pragma unroll
      for (int rr = 0; rr < 4; ++rr)
        C[(long)(row0 + rr) * ldc + col] = __float2bfloat16(acc[i][j][rr] * alpha);
    }
  }
}

// ---------------------------------------------------------------------------
// Fused fp32->bf16 converts for from/to (blockIdx.y selects). 4M elems each.
// ---------------------------------------------------------------------------
__global__ __launch_bounds__(256) void cvt2(
    const float* __restrict__ a, const float* __restrict__ b,
    bf16* __restrict__ oa, bf16* __restrict__ ob)
{
  const float* in = blockIdx.y ? b : a;
  bf16* out = blockIdx.y ? ob : oa;
  int i = (blockIdx.x * 256 + threadIdx.x) * 8;
  float4 v0 = *(const float4*)(in + i);
  float4 v1 = *(const float4*)(in + i + 4);
  uint4 pk;
  pk.x = pack2bf(v0.x, v0.y);
  pk.y = pack2bf(v0.z, v0.w);
  pk.z = pack2bf(v1.x, v1.y);
  pk.w = pack2bf(v1.z, v1.w);
  *(uint4*)(out + i) = pk;
}

// ---------------------------------------------------------------------------
// Fused 4-way weight transpose: fp32 [1024,1024] -> bf16 transposed, z=0..3.
// ---------------------------------------------------------------------------
struct WT4 { const float* s[4]; bf16* d[4]; };

__global__ __launch_bounds__(256) void wtrans4(WT4 a) {
  __shared__ bf16 tile[64][66];
  int z = blockIdx.z;
  const float* in = a.s[z];
  bf16* out = a.d[z];
  int r0 = blockIdx.x * 64, c0 = blockIdx.y * 64;
  int tx = threadIdx.x & 63, ty = threadIdx.x >> 6;
  #pragma unroll
  for (int i = 0; i < 16; ++i) {
    int rr = i * 4 + ty;
    tile[rr][tx] = __float2bfloat16(in[(long)(r0 + rr) * 1024 + c0 + tx]);
  }
  __syncthreads();
  #pragma unroll
  for (int i = 0; i < 16; ++i) {
    int rr = i * 4 + ty;
    out[(long)(c0 + rr) * 1024 + r0 + tx] = tile[tx][rr];
  }
}

// ---------------------------------------------------------------------------
// Batched 64x64-tiled bf16 transpose (V -> Vt).
// ---------------------------------------------------------------------------
__global__ __launch_bounds__(256) void transpose_bf16(
    const bf16* __restrict__ in, long i_bs1, long i_bs2, int i_rs,
    bf16* __restrict__ out, long o_bs1, long o_bs2, int o_rs, int Z2)
{
  __shared__ bf16 tile[64][66];
  int z = blockIdx.z, z1 = z / Z2, z2 = z - z1 * Z2;
  const bf16* ib = in + z1 * i_bs1 + z2 * i_bs2;
  bf16* ob = out + z1 * o_bs1 + z2 * o_bs2;
  int r0 = blockIdx.x * 64, c0 = blockIdx.y * 64;
  int tx = threadIdx.x & 63, ty = threadIdx.x >> 6;
  #pragma unroll
  for (int i = 0; i < 16; ++i) {
    int rr = i * 4 + ty;
    tile[rr][tx] = ib[(long)(r0 + rr) * i_rs + c0 + tx];
  }
  __syncthreads();
  #pragma unroll
  for (int i = 0; i < 16; ++i) {
    int rr = i * 4 + ty;
    ob[(long)(c0 + rr) * o_rs + r0 + tx] = tile[tx][rr];
  }
}

// ---------------------------------------------------------------------------
// Talking-heads core v5: v4 dataflow (512 thr, 2 t/thread, all 16 heads in
// regs) but with the l dimension PAIRED so both mix FMAs run as guaranteed
// v_pk_fma_f32 (R8 counters: ~2000 VALU instr/thread = compiler scalarized
// the f32x2*scalar pattern; pairing over l gives natural f32x2 operands).
// zinv is folded into wpost in LDS (saves 32 mul + 16 LDS reads/thread).
// ---------------------------------------------------------------------------
__global__ __launch_bounds__(512) void mixsoftmax5(
    bf16* __restrict__ sc, long sc_bs, const float* __restrict__ pre,
    const float* __restrict__ post, const int* __restrict__ mask)
{
  __shared__ float wpre[256], wpost[256];
  __shared__ f32x2 zbufp[8][512];    // pair-sums over t, [l-pair][tid]
  __shared__ f32x2 zbuf2p[8][32];
  __shared__ f32x2 zinvp[8];
  int tid = threadIdx.x;
  int f = blockIdx.x, b = blockIdx.y;
  if (tid < 256) {
    wpre[tid] = pre[tid];
    wpost[tid] = post[tid];
  }
  __syncthreads();

  unsigned short* scb = (unsigned short*)(sc + (long)b * sc_bs) + ((long)f << 10);
  const int* mk = mask + ((long)b << 20) + ((long)f << 10);
  int tg = tid * 2;

  // prefetch all 16 head-rows for this thread's 2 t's (4B each, coalesced)
  unsigned u[16];
  #pragma unroll
  for (int n = 0; n < 16; ++n)
    u[n] = *(const unsigned*)(scb + ((long)n << 20) + tg);
  int2 mm = *(const int2*)(mk + tg);
  float madd0 = (1.0f - (float)mm.x) * -10000.0f;
  float madd1 = (1.0f - (float)mm.y) * -10000.0f;

  // m0[p] = mixed[l=2p,2p+1][t0], m1[p] = same for t1
  f32x2 m0[8], m1[8];
  #pragma unroll
  for (int p = 0; p < 8; ++p) {
    m0[p] = splat2(madd0);
    m1[p] = splat2(madd1);
  }

  // pre-mix: m{t}[p] += wpre[n][pair p] * s[n][t]
  #pragma unroll
  for (int n = 0; n < 16; ++n) {
    unsigned lo = u[n];
    f32x2 sp0 = splat2(__uint_as_float((lo & 0xffffu) << 16));
    f32x2 sp1 = splat2(__uint_as_float(lo & 0xffff0000u));
    const float4* wr = (const float4*)&wpre[n * 16];
    #pragma unroll
    for (int g = 0; g < 4; ++g) {
      float4 wv = wr[g];
      f32x2 wa = {wv.x, wv.y}, wb = {wv.z, wv.w};
      m0[g * 2 + 0] = pk_fma(wa, sp0, m0[g * 2 + 0]);
      m0[g * 2 + 1] = pk_fma(wb, sp0, m0[g * 2 + 1]);
      m1[g * 2 + 0] = pk_fma(wa, sp1, m1[g * 2 + 0]);
      m1[g * 2 + 1] = pk_fma(wb, sp1, m1[g * 2 + 1]);
    }
  }

  // exp (no max subtraction: |mixed| ~ O(1); masked -> underflow to 0)
  #pragma unroll
  for (int p = 0; p < 8; ++p) {
    m0[p].x = __expf(m0[p].x);  m0[p].y = __expf(m0[p].y);
    m1[p].x = __expf(m1[p].x);  m1[p].y = __expf(m1[p].y);
    zbufp[p][tid] = m0[p] + m1[p];
  }
  __syncthreads();
  if (tid < 256) {
    int p = tid >> 5, c = tid & 31;
    const f32x2* zr = &zbufp[p][c * 16];
    f32x2 s = zr[0];
    #pragma unroll
    for (int i = 1; i < 16; ++i) s += zr[i];
    zbuf2p[p][c] = s;
  }
  __syncthreads();
  if (tid < 8) {
    f32x2 s = zbuf2p[tid][0];
    #pragma unroll
    for (int g = 1; g < 32; ++g) s += zbuf2p[tid][g];
    zinvp[tid] = (f32x2){1.0f / s.x, 1.0f / s.y};
  }
  __syncthreads();
  // fold zinv into wpost (in place; each thread touches only wpost[tid])
  if (tid < 256) {
    int n = tid >> 4;
    float zi = (n & 1) ? zinvp[n >> 1].y : zinvp[n >> 1].x;
    wpost[tid] *= zi;
  }
  __syncthreads();

  // post-mix on unnormalized E with pre-scaled wpost
  f32x2 o0[8], o1[8];
  #pragma unroll
  for (int p = 0; p < 8; ++p) {
    o0[p] = splat2(0.0f);
    o1[p] = splat2(0.0f);
  }
  #pragma unroll
  for (int n = 0; n < 16; ++n) {
    int p = n >> 1;
    float e0 = (n & 1) ? m0[p].y : m0[p].x;
    float e1 = (n & 1) ? m1[p].y : m1[p].x;
    f32x2 sp0 = splat2(e0), sp1 = splat2(e1);
    const float4* wr = (const float4*)&wpost[n * 16];
    #pragma unroll
    for (int g = 0; g < 4; ++g) {
      float4 wv = wr[g];
      f32x2 wa = {wv.x, wv.y}, wb = {wv.z, wv.w};
      o0[g * 2 + 0] = pk_fma(wa, sp0, o0[g * 2 + 0]);
      o0[g * 2 + 1] = pk_fma(wb, sp0, o0[g * 2 + 1]);
      o1[g * 2 + 0] = pk_fma(wa, sp1, o1[g * 2 + 0]);
      o1[g * 2 + 1] = pk_fma(wb, sp1, o1[g * 2 + 1]);
    }
  }
  #pragma unroll
  for (int l = 0; l < 16; ++l) {
    int p = l >> 1;
    float a0 = (l & 1) ? o0[p].y : o0[p].x;
    float a1 = (l & 1) ? o1[p].y : o1[p].x;
    *(unsigned*)(scb + ((long)l << 20) + tg) = pack2bf(a0, a1);
  }
}

// ---------------------------------------------------------------------------
// B=4, S=1024, D=1024, N=16, H=64. fp32 I/O, bf16 internal.
// ws (bf16 elems, M1=1<<20): big path 85M = 170 MB (Sc 64M overlapping the
// dead phase-1 staging), small path 37M = 74 MB (per-batch Sc 16M).
// ---------------------------------------------------------------------------
extern "C" void kernel_launch(void* const* d_in, const int* in_sizes, int n_in,
                              void* d_out, int out_size, void* d_ws, size_t ws_size,
                              hipStream_t stream) {
  const float* from = (const float*)d_in[0];
  const float* to   = (const float*)d_in[1];
  const int*  mask  = (const int*)d_in[2];
  const float* wq = (const float*)d_in[3];
  const float* bq = (const float*)d_in[4];
  const float* wk = (const float*)d_in[5];
  const float* bk = (const float*)d_in[6];
  const float* wv = (const float*)d_in[7];
  const float* bv = (const float*)d_in[8];
  const float* pre  = (const float*)d_in[9];
  const float* post = (const float*)d_in[10];
  const float* wo = (const float*)d_in[11];
  const float* bo = (const float*)d_in[12];
  float* out = (float*)d_out;

  bf16* W = (bf16*)d_ws;
  const long M1 = 1048576;
  bool big = ws_size >= (size_t)(85 * M1) * 2;

  bf16 *Sc, *fromB, *toB, *wqT, *wkT, *wvT, *woT, *Q, *Kp, *V, *Vt, *ctx;
  if (big) {
    Sc = W;                 fromB = W;            toB = W + 4 * M1;
    wqT = W + 8 * M1;       wkT = W + 9 * M1;     wvT = W + 10 * M1;
    woT = W + 64 * M1;      Q = W + 65 * M1;      Kp = W + 69 * M1;
    V = W + 73 * M1;        Vt = W + 77 * M1;     ctx = W + 81 * M1;
  } else {
    Sc = W;                 fromB = W;            toB = W + 4 * M1;
    wqT = W + 8 * M1;       wkT = W + 9 * M1;     wvT = W + 10 * M1;
    woT = W + 16 * M1;      Q = W + 17 * M1;      Kp = W + 21 * M1;
    V = W + 25 * M1;        Vt = W + 29 * M1;     ctx = W + 33 * M1;
  }

  dim3 blk(256);

  // 1) converts (1 dispatch) + weight transposes (1 dispatch)
  cvt2<<<dim3(2048, 2), blk, 0, stream>>>(from, to, fromB, toB);
  WT4 wt;
  wt.s[0] = wq; wt.s[1] = wk; wt.s[2] = wv; wt.s[3] = wo;
  wt.d[0] = wqT; wt.d[1] = wkT; wt.d[2] = wvT; wt.d[3] = woT;
  wtrans4<<<dim3(16, 16, 4), blk, 0, stream>>>(wt);

  // 2) QKV projections, z-batched (1 dispatch), 128x64 tiles (512 blocks/z)
  QKVArgs qa;
  qa.A[0] = fromB; qa.A[1] = toB; qa.A[2] = toB;
  qa.Bw[0] = wqT;  qa.Bw[1] = wkT; qa.Bw[2] = wvT;
  qa.C[0] = Q;     qa.C[1] = Kp;  qa.C[2] = V;
  qa.bias[0] = bq; qa.bias[1] = bk; qa.bias[2] = bv;
  gemm_qkv<<<dim3(32, 16, 3), blk, 0, stream>>>(qa);

  // 3) V [B,S,N,H] -> Vt [B,N,H,S]
  transpose_bf16<<<dim3(16, 1, 64), blk, 0, stream>>>(V, M1, 64, 1024,
                                                      Vt, M1, 65536, 1024, 16);

  if (big) {
    // 4) scores (direct K=64): z=(b,n): Sc[b,n] = 0.125*Q[b,:,n,:]@K[b,:,n,:]^T
    gemm_k64<<<dim3(8, 8, 64), blk, 0, stream>>>(
        Q, M1, 64, 1024, Kp, M1, 64, 1024, Sc, 16 * M1, M1, 1024, 16, 0.125f);
    // 5) talking-heads softmax (512-thread, 2 t/thread, packed-f32 mixes)
    mixsoftmax5<<<dim3(1024, 4), dim3(512), 0, stream>>>(Sc, 16 * M1, pre, post, mask);
    // 6) PV: z=(b,l): ctx[b,:,l,:] = Sc[b,l]@Vt[b,l]^T
    gemm_lds64<<<dim3(8, 1, 64), blk, 0, stream>>>(
        Sc, 16 * M1, M1, 1024, Vt, M1, 65536, 1024, ctx, M1, 64, 1024, nullptr,
        1024, 16, 1.0f, 0);
  } else {
    for (int b = 0; b < 4; ++b) {
      gemm_k64<<<dim3(8, 8, 16), blk, 0, stream>>>(
          Q + b * M1, 0, 64, 1024, Kp + b * M1, 0, 64, 1024,
          Sc, 0, M1, 1024, 16, 0.125f);
      mixsoftmax5<<<dim3(1024, 1), dim3(512), 0, stream>>>(Sc, 0, pre, post, mask + b * M1);
      gemm_lds64<<<dim3(8, 1, 16), blk, 0, stream>>>(
          Sc, 0, M1, 1024, Vt + b * M1, 0, 65536, 1024,
          ctx + b * M1, 0, 64, 1024, nullptr, 1024, 16, 1.0f, 0);
    }
  }

  // 7) out = ctx [4096,1024] @ woT^T + bo -> d_out (fp32)
  gemm_lds64<<<dim3(32, 16, 1), blk, 0, stream>>>(
      ctx, 0, 0, 1024, woT, 0, 0, 1024, out, 0, 0, 1024, bo, 1024, 1, 1.0f, 1);
}